// Round 9
// baseline (201.443 us; speedup 1.0000x reference)
//
#include <hip/hip_runtime.h>

// Problem constants (B=16, C=64, H=64, W=64, K=1024, D=64)
#define HWSZ   4096
#define CCH    64
#define KCB    1024
#define NROW   65536
#define NDTOT  4194304
#define MBLK   1024            // main-path blocks (64 rows each)

typedef __attribute__((ext_vector_type(8))) short short8;
typedef __attribute__((ext_vector_type(4))) float f32x4;

__device__ __forceinline__ unsigned short f2bf_rn(float x) {
    union { float f; unsigned u; } v; v.f = x;
    unsigned r = (v.u + 0x7fffu + ((v.u >> 16) & 1u)) >> 16;
    return (unsigned short)r;
}

// ---------- prep: 16 blocks, 4 threads/code: E -> swizzled bf16 + he2b + counter=0 ----------
__global__ __launch_bounds__(256) void vq_prep(const float* __restrict__ E,
                                               unsigned* __restrict__ Ebf,
                                               float* __restrict__ he2b,
                                               unsigned* __restrict__ counter) {
    const int t = threadIdx.x;
    if (blockIdx.x == 0 && t == 0) *counter = 0u;
    const int gid  = blockIdx.x * 256 + t;
    const int code = gid >> 2;           // 0..1023
    const int part = gid & 3;
    const float4* ep = (const float4*)(E + (size_t)code * 64 + part * 16);
    const unsigned sw = ((unsigned)code & 7u) << 2;   // T2 swizzle on dword index
    float s = 0.f;
    #pragma unroll
    for (int q = 0; q < 4; ++q) {
        float4 a = ep[q];
        s += a.x * a.x + a.y * a.y + a.z * a.z + a.w * a.w;
        unsigned lo = (unsigned)f2bf_rn(a.x) | ((unsigned)f2bf_rn(a.y) << 16);
        unsigned hi = (unsigned)f2bf_rn(a.z) | ((unsigned)f2bf_rn(a.w) << 16);
        unsigned base = (unsigned)code * 32 + part * 8 + q * 2;
        Ebf[base ^ sw]       = lo;       // (base+1)^sw == (base^sw)+1 (sw bits >= 2)
        Ebf[(base + 1) ^ sw] = hi;
    }
    s += __shfl_xor(s, 1, 64);
    s += __shfl_xor(s, 2, 64);
    if (part == 0) he2b[code] = 1.0f + 0.5f * s;
}

// ---------- main: 1024 blocks x 256 thr; block = 64 rows; wave = 64 rows x 256 codes ----------
// Each wave streams its own 4KB code-chunks through its own LDS buffer: NO barriers
// in the scan loop (waves fully asynchronous; 16 waves/CU hide latency). rt=4 halves
// LDS-read per MFMA. Final losses folded in via last-block atomic ticket.
__global__ __launch_bounds__(256, 2) void vq_mfma(const float* __restrict__ z,
                                                  const float* __restrict__ E,
                                                  const short* __restrict__ Ebf,
                                                  const float* __restrict__ he2g,
                                                  float* __restrict__ out,
                                                  float* __restrict__ partial,
                                                  unsigned* __restrict__ counter) {
    __shared__ short lbs[2][4][2048];      // per-wave double-buffered 4KB chunks (32 KB)
    __shared__ unsigned wpack[4][64];
    __shared__ int rowidx[64];
    __shared__ float wsum[4];
    __shared__ unsigned sflag;

    const int t   = threadIdx.x;           // 0..255
    const int blk = blockIdx.x;            // 0..1023
    const int n0  = blk << 6;              // 64 rows
    const int bb  = n0 >> 12;
    const int hw0 = n0 & 4095;
    const int wid = t >> 6, lane = t & 63, col = lane & 15, g = lane >> 4;
    const float* zw = z + (size_t)bb * CCH * HWSZ + hw0;

    // ---- A-frags rt=4 (rows rt*16+col) + z^2 (identical across waves -> use wave 0's) ----
    float z2 = 0.f;
    short8 af[4][2];
    #pragma unroll
    for (int rt = 0; rt < 4; ++rt) {
        const int i = rt * 16 + col;
        #pragma unroll
        for (int ch = 0; ch < 2; ++ch) {
            short8 a;
            #pragma unroll
            for (int j = 0; j < 8; ++j) {
                int c = ch * 32 + g * 8 + j;
                float v = zw[(size_t)c * HWSZ + i];
                z2 = fmaf(v, v, z2);
                union { float f; unsigned u; } uu; uu.f = v;
                a[j] = (short)((uu.u >> 16) ^ 0x8000u);   // -z, bf16 truncation
            }
            af[rt][ch] = a;
        }
    }

    // ---- bias prefetch: wave's 16 code-tiles ----
    float hvv[16];
    #pragma unroll
    for (int q = 0; q < 16; ++q) hvv[q] = he2g[wid * 256 + q * 16 + col];

    // ---- prologue: stage chunk 0 of wave's quarter (codes [wid*256, +32)) ----
    const short8* gB = (const short8*)Ebf;           // 16B units; 8 units per code row
    const int ub0 = wid * 2048;                      // wave quarter base (256 codes * 8)
    {
        short8 s0 = gB[ub0 + 0 * 64 + lane];
        short8 s1 = gB[ub0 + 1 * 64 + lane];
        short8 s2 = gB[ub0 + 2 * 64 + lane];
        short8 s3 = gB[ub0 + 3 * 64 + lane];
        short8* Ld = (short8*)lbs[0][wid];
        Ld[0 * 64 + lane] = s0; Ld[1 * 64 + lane] = s1;
        Ld[2 * 64 + lane] = s2; Ld[3 * 64 + lane] = s3;
    }

    float pk[4][4];
    #pragma unroll
    for (int rt = 0; rt < 4; ++rt)
        #pragma unroll
        for (int r = 0; r < 4; ++r) pk[rt][r] = 3.0e38f;

    const int swz = (col & 7) << 3;                  // swizzle in shorts
    const int roA = (g * 8) ^ swz;
    const int roB = (32 + g * 8) ^ swz;

    // ---- 8 chunk steps, barrier-free (per-wave LDS ownership) ----
    #pragma unroll
    for (int i = 0; i < 8; ++i) {
        short8 s0, s1, s2, s3;
        if (i < 7) {                                 // issue-early next chunk
            const int ub = ub0 + (i + 1) * 256;
            s0 = gB[ub + 0 * 64 + lane];
            s1 = gB[ub + 1 * 64 + lane];
            s2 = gB[ub + 2 * 64 + lane];
            s3 = gB[ub + 3 * 64 + lane];
        }
        const short* Lb = lbs[i & 1][wid];
        short8 b00 = *(const short8*)(Lb + (0 * 16 + col) * 64 + roA);
        short8 b01 = *(const short8*)(Lb + (0 * 16 + col) * 64 + roB);
        short8 b10 = *(const short8*)(Lb + (1 * 16 + col) * 64 + roA);
        short8 b11 = *(const short8*)(Lb + (1 * 16 + col) * 64 + roB);
        const unsigned code0 = (unsigned)(wid * 256 + i * 32 + col);
        const unsigned code1 = code0 + 16;
        const float h0 = hvv[i * 2 + 0], h1 = hvv[i * 2 + 1];
        f32x4 hv0 = {h0, h0, h0, h0};
        f32x4 hv1 = {h1, h1, h1, h1};
        #pragma unroll
        for (int rt = 0; rt < 4; ++rt) {
            f32x4 a0 = __builtin_amdgcn_mfma_f32_16x16x32_bf16(af[rt][0], b00, hv0, 0, 0, 0);
            a0 = __builtin_amdgcn_mfma_f32_16x16x32_bf16(af[rt][1], b01, a0, 0, 0, 0);
            f32x4 a1 = __builtin_amdgcn_mfma_f32_16x16x32_bf16(af[rt][0], b10, hv1, 0, 0, 0);
            a1 = __builtin_amdgcn_mfma_f32_16x16x32_bf16(af[rt][1], b11, a1, 0, 0, 0);
            #pragma unroll
            for (int r = 0; r < 4; ++r) {
                union { float f; unsigned u; } m0, m1;
                m0.f = a0[r]; m0.u = (m0.u & 0xFFFFFC00u) | code0;   // v_and_or_b32
                m1.f = a1[r]; m1.u = (m1.u & 0xFFFFFC00u) | code1;
                pk[rt][r] = fminf(fminf(pk[rt][r], m0.f), m1.f);     // v_min3_f32
            }
        }
        if (i < 7) {                                 // write-late into other buffer
            short8* Ld = (short8*)lbs[(i + 1) & 1][wid];
            Ld[0 * 64 + lane] = s0; Ld[1 * 64 + lane] = s1;
            Ld[2 * 64 + lane] = s2; Ld[3 * 64 + lane] = s3;
        }
    }

    // ---- butterfly min over 16 code-columns; publish per-wave row answers ----
    #pragma unroll
    for (int rt = 0; rt < 4; ++rt) {
        #pragma unroll
        for (int r = 0; r < 4; ++r) {
            float d = pk[rt][r];
            #pragma unroll
            for (int mask = 1; mask < 16; mask <<= 1)
                d = fminf(d, __shfl_xor(d, mask, 64));
            if (col == 0) {
                union { float f; unsigned u; } b; b.f = d;
                wpack[wid][rt * 16 + g * 4 + r] = b.u;
            }
        }
    }
    // z^2 wave reduce (waves compute identical z2; wave 0's is used)
    #pragma unroll
    for (int off = 32; off >= 1; off >>= 1) z2 += __shfl_down(z2, off, 64);
    if (lane == 0) wsum[wid] = z2;
    __syncthreads();

    if (t < 64) {   // combine 4 code-quarters; loss from winning scores
        unsigned u0 = wpack[0][t], u1 = wpack[1][t];
        unsigned u2 = wpack[2][t], u3 = wpack[3][t];
        unsigned m01 = u0 < u1 ? u0 : u1;
        unsigned m23 = u2 < u3 ? u2 : u3;
        unsigned m = m01 < m23 ? m01 : m23;
        rowidx[t] = (int)(m & 1023u);
        union { unsigned u; float f; } sc; sc.u = m & 0xFFFFFC00u;
        float scv = 2.0f * (sc.f - 1.0f);            // ||e||^2 - 2 z.e
        #pragma unroll
        for (int off = 32; off >= 1; off >>= 1) scv += __shfl_down(scv, off, 64);
        if (t == 0) partial[blk] = wsum[0] + scv;
    }
    __syncthreads();

    // ---- output = E rows (== z + (q - z) to 1 ulp), float4 coalesced ----
    const int d0i = (t & 15) * 4;
    const int r0  = t >> 4;                          // 0..15
    float* ob = out + (size_t)n0 * 64;
    #pragma unroll
    for (int jj = 0; jj < 4; ++jj) {
        int nl = r0 + 16 * jj;
        int k  = rowidx[nl];                         // uniform per 16-lane group
        float4 qv = *(const float4*)(E + (size_t)k * 64 + d0i);
        *(float4*)(ob + (size_t)nl * 64 + d0i) = qv;
    }

    // ---- last-block ticket: finalize losses (replaces vq_fin launch) ----
    __threadfence();
    if (t == 0) sflag = (atomicAdd(counter, 1u) == (MBLK - 1)) ? 1u : 0u;
    __syncthreads();
    if (sflag) {
        __threadfence();
        float s = 0.f;
        #pragma unroll
        for (int q = 0; q < 4; ++q) s += partial[q * 256 + t];
        float* ps = (float*)wpack;                   // reuse as 256-float scratch
        ps[t] = s;
        __syncthreads();
        for (int st = 128; st >= 1; st >>= 1) {
            if (t < st) ps[t] += ps[t + st];
            __syncthreads();
        }
        if (t == 0) {
            float mse = ps[0] / (float)NDTOT;
            out[NDTOT]     = 0.25f * mse;            // commitment_loss
            out[NDTOT + 1] = mse;                    // codebook_loss
        }
    }
}

// ---------- fallback fp32 path (round-1, correctness-proven) ----------
__global__ __launch_bounds__(64) void vq_init(float* out) {
    if (threadIdx.x == 0) { out[NDTOT] = 0.0f; out[NDTOT + 1] = 0.0f; }
}

__global__ __launch_bounds__(256, 4) void vq_main_fp32(const float* __restrict__ z,
                                                       const float* __restrict__ E,
                                                       float* __restrict__ out,
                                                       float* __restrict__ partial) {
    __shared__ float zs[64][65];
    __shared__ float e2s[KCB];
    __shared__ float wmin[4][64];
    __shared__ int   widx[4][64];
    __shared__ int   rowidx[64];
    __shared__ float wsum[4];

    const int t   = threadIdx.x;
    const int blk = blockIdx.x;
    const int n0  = blk << 6;
    const int bb  = n0 >> 12;
    const int hw0 = n0 & 4095;
    const float* zb = z + (size_t)bb * CCH * HWSZ + hw0;

    #pragma unroll
    for (int j = 0; j < 16; ++j) {
        int f = t + 256 * j;
        int c = f >> 6, i = f & 63;
        zs[c][i] = zb[(size_t)c * HWSZ + i];
    }
    for (int qq = t; qq < KCB; qq += 256) {
        const float4* ep = (const float4*)(E + (size_t)qq * 64);
        float s0 = 0.f;
        #pragma unroll
        for (int c4 = 0; c4 < 16; ++c4) {
            float4 a = ep[c4];
            s0 += a.x * a.x + a.y * a.y + a.z * a.z + a.w * a.w;
        }
        e2s[qq] = s0;
    }
    __syncthreads();

    const int i   = t & 63;
    const int wid = t >> 6;
    float zr[64];
    #pragma unroll
    for (int c = 0; c < 64; ++c) zr[c] = zs[c][i];

    float best = 3.4e38f;
    int   bi = 0;
    const int k0 = wid << 8;
    const float* Ew = E + (size_t)k0 * 64;
    for (int kk = 0; kk < 256; ++kk) {
        const float4* ek = (const float4*)(Ew + (size_t)kk * 64);
        float d0 = 0.f, d1 = 0.f, d2 = 0.f, d3 = 0.f;
        #pragma unroll
        for (int c4 = 0; c4 < 16; ++c4) {
            float4 a = ek[c4];
            d0 = fmaf(a.x, zr[4 * c4 + 0], d0);
            d1 = fmaf(a.y, zr[4 * c4 + 1], d1);
            d2 = fmaf(a.z, zr[4 * c4 + 2], d2);
            d3 = fmaf(a.w, zr[4 * c4 + 3], d3);
        }
        float dot  = (d0 + d1) + (d2 + d3);
        float dist = fmaf(-2.0f, dot, e2s[k0 + kk]);
        if (dist < best) { best = dist; bi = k0 + kk; }
    }
    wmin[wid][i] = best; widx[wid][i] = bi;
    __syncthreads();
    if (t < 64) {
        float m = wmin[0][t]; int ix = widx[0][t];
        #pragma unroll
        for (int w = 1; w < 4; ++w) {
            float v = wmin[w][t]; int x = widx[w][t];
            if (v < m) { m = v; ix = x; }
        }
        rowidx[t] = ix;
    }
    __syncthreads();

    float lsum = 0.f;
    const size_t base = (size_t)blk * 4096;
    float* oflat = out + base;
    #pragma unroll
    for (int j = 0; j < 16; ++j) {
        int f  = t + 256 * j;
        int nl = f >> 6, d = f & 63;
        int k  = rowidx[nl];
        float qv = E[(size_t)k * 64 + d];
        float zf = zs[d][nl];
        float df = qv - zf;
        lsum += df * df;
        oflat[f] = qv;
    }
    #pragma unroll
    for (int off = 32; off >= 1; off >>= 1) lsum += __shfl_down(lsum, off, 64);
    if (i == 0) wsum[wid] = lsum;
    __syncthreads();
    if (t == 0) {
        float s = (wsum[0] + wsum[1]) + (wsum[2] + wsum[3]);
        if (partial) partial[blk] = s;
        else         atomicAdd(&out[NDTOT + 1], s);
    }
}

__global__ __launch_bounds__(256) void vq_fin(const float* __restrict__ partial,
                                              float* __restrict__ out, int npart) {
    if (npart > 0) {
        __shared__ float ps[256];
        float s = 0.f;
        for (int qq = threadIdx.x; qq < npart; qq += 256) s += partial[qq];
        ps[threadIdx.x] = s;
        __syncthreads();
        for (int st = 128; st >= 1; st >>= 1) {
            if (threadIdx.x < st) ps[threadIdx.x] += ps[threadIdx.x + st];
            __syncthreads();
        }
        if (threadIdx.x == 0) {
            float mse = ps[0] / (float)NDTOT;
            out[NDTOT]     = 0.25f * mse;   // commitment_loss
            out[NDTOT + 1] = mse;           // codebook_loss
        }
    } else {
        if (threadIdx.x == 0) {
            float mse = out[NDTOT + 1] / (float)NDTOT;
            out[NDTOT]     = 0.25f * mse;
            out[NDTOT + 1] = mse;
        }
    }
}

extern "C" void kernel_launch(void* const* d_in, const int* in_sizes, int n_in,
                              void* d_out, int out_size, void* d_ws, size_t ws_size,
                              hipStream_t stream) {
    const float* z = (const float*)d_in[0];
    const float* E = (const float*)d_in[1];
    float* out = (float*)d_out;

    const size_t EBF_BYTES = (size_t)KCB * 64 * 2;                 // 131072
    const size_t HE2_OFF   = EBF_BYTES;                            // 4 KB
    const size_t PART_OFF  = EBF_BYTES + 4096;                     // 4 KB (1024 floats)
    const size_t CNT_OFF   = EBF_BYTES + 4096 + 4096;
    const size_t need      = CNT_OFF + 64;

    if (ws_size >= need) {
        unsigned* EbfU    = (unsigned*)d_ws;
        short*    Ebf     = (short*)d_ws;
        float*    he2b    = (float*)((char*)d_ws + HE2_OFF);
        float*    partial = (float*)((char*)d_ws + PART_OFF);
        unsigned* counter = (unsigned*)((char*)d_ws + CNT_OFF);
        hipLaunchKernelGGL(vq_prep, dim3(16), dim3(256), 0, stream, E, EbfU, he2b, counter);
        hipLaunchKernelGGL(vq_mfma, dim3(MBLK), dim3(256), 0, stream,
                           z, E, Ebf, he2b, out, partial, counter);
    } else {
        float* partial = (ws_size >= KCB * sizeof(float)) ? (float*)d_ws : nullptr;
        int npart = (partial != nullptr) ? KCB : 0;
        hipLaunchKernelGGL(vq_init, dim3(1), dim3(64), 0, stream, out);
        hipLaunchKernelGGL(vq_main_fp32, dim3(1024), dim3(256), 0, stream, z, E, out, partial);
        hipLaunchKernelGGL(vq_fin, dim3(1), dim3(256), 0, stream, partial, out, npart);
    }
}

// Round 10
// 198.894 us; speedup vs baseline: 1.0128x; 1.0128x over previous
//
#include <hip/hip_runtime.h>

// Problem constants (B=16, C=64, H=64, W=64, K=1024, D=64)
#define HWSZ   4096
#define CCH    64
#define KCB    1024
#define NROW   65536
#define NDTOT  4194304
#define MBLK   1024            // main-path blocks (64 rows each)

typedef __attribute__((ext_vector_type(8))) short short8;
typedef __attribute__((ext_vector_type(4))) float f32x4;

typedef const __attribute__((address_space(1))) unsigned gas_u32;
typedef __attribute__((address_space(3))) unsigned las_u32;

__device__ __forceinline__ unsigned short f2bf_rn(float x) {
    union { float f; unsigned u; } v; v.f = x;
    unsigned r = (v.u + 0x7fffu + ((v.u >> 16) & 1u)) >> 16;
    return (unsigned short)r;
}

// ---------- prep: 16 blocks, 4 threads/code: E -> swizzled bf16 + he2b + counter=0 ----------
__global__ __launch_bounds__(256) void vq_prep(const float* __restrict__ E,
                                               unsigned* __restrict__ Ebf,
                                               float* __restrict__ he2b,
                                               unsigned* __restrict__ counter) {
    const int t = threadIdx.x;
    if (blockIdx.x == 0 && t == 0) *counter = 0u;
    const int gid  = blockIdx.x * 256 + t;
    const int code = gid >> 2;           // 0..1023
    const int part = gid & 3;
    const float4* ep = (const float4*)(E + (size_t)code * 64 + part * 16);
    const unsigned sw = ((unsigned)code & 7u) << 2;   // T2 swizzle on dword index
    float s = 0.f;
    #pragma unroll
    for (int q = 0; q < 4; ++q) {
        float4 a = ep[q];
        s += a.x * a.x + a.y * a.y + a.z * a.z + a.w * a.w;
        unsigned lo = (unsigned)f2bf_rn(a.x) | ((unsigned)f2bf_rn(a.y) << 16);
        unsigned hi = (unsigned)f2bf_rn(a.z) | ((unsigned)f2bf_rn(a.w) << 16);
        unsigned base = (unsigned)code * 32 + part * 8 + q * 2;
        Ebf[base ^ sw]       = lo;       // (base+1)^sw == (base^sw)+1 (sw bits >= 2)
        Ebf[(base + 1) ^ sw] = hi;
    }
    s += __shfl_xor(s, 1, 64);
    s += __shfl_xor(s, 2, 64);
    if (part == 0) he2b[code] = 1.0f + 0.5f * s;
}

// ---------- main: 1024 blocks x 256 thr; block = 64 rows; wave = 64 rows x 256 codes ----------
// Chunks staged via global_load_lds (zero staging VGPRs) + per-wave counted vmcnt(4):
// no barriers, no reg staging. rt=4 -> 1 ds_read_b128 feeds 4 MFMA. 4 blocks/CU supply.
// launch_bounds (256,2): cap 128 VGPR; demand ~105 (r9 spilled at ~140 -> gload_lds fix).
__global__ __launch_bounds__(256, 2) void vq_mfma(const float* __restrict__ z,
                                                  const float* __restrict__ E,
                                                  const short* __restrict__ Ebf,
                                                  const float* __restrict__ he2g,
                                                  float* __restrict__ out,
                                                  float* __restrict__ partial,
                                                  unsigned* __restrict__ counter) {
    __shared__ short lbs[2][4][2048];      // per-wave double-buffered 4KB chunks (32 KB)
    __shared__ unsigned wpack[4][64];
    __shared__ int rowidx[64];
    __shared__ float wsum[4];
    __shared__ unsigned sflag;

    const int t   = threadIdx.x;           // 0..255
    const int blk = blockIdx.x;            // 0..1023
    const int n0  = blk << 6;              // 64 rows
    const int bb  = n0 >> 12;
    const int hw0 = n0 & 4095;
    const int wid = t >> 6, lane = t & 63, col = lane & 15, g = lane >> 4;
    const float* zw = z + (size_t)bb * CCH * HWSZ + hw0;

    // wave's codebook quarter in (pre-swizzled) global Ebf: 256 codes = 32 KB, chunk = 4 KB
    const char* gq = (const char*)Ebf + (size_t)wid * 32768 + (size_t)lane * 16;

    // ---- prologue: DMA chunk 0 into buf 0 (4 x 1KB, vmcnt += 4) ----
    #pragma unroll
    for (int i = 0; i < 4; ++i)
        __builtin_amdgcn_global_load_lds((gas_u32*)(gq + i * 1024),
                                         (las_u32*)((char*)lbs[0][wid] + i * 1024), 16, 0, 0);

    // ---- A-frags rt=4 (rows rt*16+col) + z^2, direct from global (compiler-tracked) ----
    float z2 = 0.f;
    short8 af[4][2];
    #pragma unroll
    for (int rt = 0; rt < 4; ++rt) {
        const int i = rt * 16 + col;
        #pragma unroll
        for (int ch = 0; ch < 2; ++ch) {
            short8 a;
            #pragma unroll
            for (int j = 0; j < 8; ++j) {
                int c = ch * 32 + g * 8 + j;
                float v = zw[(size_t)c * HWSZ + i];
                z2 = fmaf(v, v, z2);
                union { float f; unsigned u; } uu; uu.f = v;
                a[j] = (short)((uu.u >> 16) ^ 0x8000u);   // -z, bf16 truncation
            }
            af[rt][ch] = a;
        }
    }

    // ---- bias prefetch: wave's 16 code-tiles ----
    float hvv[16];
    #pragma unroll
    for (int q = 0; q < 16; ++q) hvv[q] = he2g[wid * 256 + q * 16 + col];

    float pk[4][4];
    #pragma unroll
    for (int rt = 0; rt < 4; ++rt)
        #pragma unroll
        for (int r = 0; r < 4; ++r) pk[rt][r] = 3.0e38f;

    const int swz = (col & 7) << 3;                  // swizzle in shorts (16B units)
    const int roA = (g * 8) ^ swz;
    const int roB = (32 + g * 8) ^ swz;

    // ---- 8 chunk steps, barrier-free; counted vmcnt keeps next chunk in flight ----
    #pragma unroll
    for (int c = 0; c < 8; ++c) {
        if (c < 7) {                                 // issue next chunk -> other buffer
            const char* gn = gq + (size_t)(c + 1) * 4096;
            char* ld = (char*)lbs[(c + 1) & 1][wid];
            #pragma unroll
            for (int i = 0; i < 4; ++i)
                __builtin_amdgcn_global_load_lds((gas_u32*)(gn + i * 1024),
                                                 (las_u32*)(ld + i * 1024), 16, 0, 0);
            asm volatile("s_waitcnt vmcnt(4)" ::: "memory");   // chunk c landed (4 newest = c+1)
        } else {
            asm volatile("s_waitcnt vmcnt(0)" ::: "memory");   // last chunk: drain
        }
        __builtin_amdgcn_sched_barrier(0);           // rule #18: pin reads after the wait

        const short* Lb = lbs[c & 1][wid];
        short8 b00 = *(const short8*)(Lb + (0 * 16 + col) * 64 + roA);
        short8 b01 = *(const short8*)(Lb + (0 * 16 + col) * 64 + roB);
        short8 b10 = *(const short8*)(Lb + (1 * 16 + col) * 64 + roA);
        short8 b11 = *(const short8*)(Lb + (1 * 16 + col) * 64 + roB);
        const unsigned code0 = (unsigned)(wid * 256 + c * 32 + col);
        const unsigned code1 = code0 + 16;
        const float h0 = hvv[c * 2 + 0], h1 = hvv[c * 2 + 1];
        f32x4 hv0 = {h0, h0, h0, h0};
        f32x4 hv1 = {h1, h1, h1, h1};
        #pragma unroll
        for (int rt = 0; rt < 4; ++rt) {
            f32x4 a0 = __builtin_amdgcn_mfma_f32_16x16x32_bf16(af[rt][0], b00, hv0, 0, 0, 0);
            a0 = __builtin_amdgcn_mfma_f32_16x16x32_bf16(af[rt][1], b01, a0, 0, 0, 0);
            f32x4 a1 = __builtin_amdgcn_mfma_f32_16x16x32_bf16(af[rt][0], b10, hv1, 0, 0, 0);
            a1 = __builtin_amdgcn_mfma_f32_16x16x32_bf16(af[rt][1], b11, a1, 0, 0, 0);
            #pragma unroll
            for (int r = 0; r < 4; ++r) {
                union { float f; unsigned u; } m0, m1;
                m0.f = a0[r]; m0.u = (m0.u & 0xFFFFFC00u) | code0;   // v_and_or_b32
                m1.f = a1[r]; m1.u = (m1.u & 0xFFFFFC00u) | code1;
                pk[rt][r] = fminf(fminf(pk[rt][r], m0.f), m1.f);     // v_min3_f32
            }
        }
    }

    // ---- butterfly min over 16 code-columns; publish per-wave row answers ----
    #pragma unroll
    for (int rt = 0; rt < 4; ++rt) {
        #pragma unroll
        for (int r = 0; r < 4; ++r) {
            float d = pk[rt][r];
            #pragma unroll
            for (int mask = 1; mask < 16; mask <<= 1)
                d = fminf(d, __shfl_xor(d, mask, 64));
            if (col == 0) {
                union { float f; unsigned u; } b; b.f = d;
                wpack[wid][rt * 16 + g * 4 + r] = b.u;
            }
        }
    }
    // z^2 wave reduce (identical across waves; wave 0's used)
    #pragma unroll
    for (int off = 32; off >= 1; off >>= 1) z2 += __shfl_down(z2, off, 64);
    if (lane == 0) wsum[wid] = z2;
    __syncthreads();

    if (t < 64) {   // combine 4 code-quarters; loss from winning scores
        unsigned u0 = wpack[0][t], u1 = wpack[1][t];
        unsigned u2 = wpack[2][t], u3 = wpack[3][t];
        unsigned m01 = u0 < u1 ? u0 : u1;
        unsigned m23 = u2 < u3 ? u2 : u3;
        unsigned m = m01 < m23 ? m01 : m23;
        rowidx[t] = (int)(m & 1023u);
        union { unsigned u; float f; } sc; sc.u = m & 0xFFFFFC00u;
        float scv = 2.0f * (sc.f - 1.0f);            // ||e||^2 - 2 z.e
        #pragma unroll
        for (int off = 32; off >= 1; off >>= 1) scv += __shfl_down(scv, off, 64);
        if (t == 0) partial[blk] = wsum[0] + scv;
    }
    __syncthreads();

    // ---- output = E rows (== z + (q - z) to 1 ulp), float4 coalesced ----
    const int d0i = (t & 15) * 4;
    const int r0  = t >> 4;                          // 0..15
    float* ob = out + (size_t)n0 * 64;
    #pragma unroll
    for (int jj = 0; jj < 4; ++jj) {
        int nl = r0 + 16 * jj;
        int k  = rowidx[nl];                         // uniform per 16-lane group
        float4 qv = *(const float4*)(E + (size_t)k * 64 + d0i);
        *(float4*)(ob + (size_t)nl * 64 + d0i) = qv;
    }

    // ---- last-block ticket: finalize losses (no separate fin launch) ----
    __threadfence();
    if (t == 0) sflag = (atomicAdd(counter, 1u) == (MBLK - 1)) ? 1u : 0u;
    __syncthreads();
    if (sflag) {
        __threadfence();
        float s = 0.f;
        #pragma unroll
        for (int q = 0; q < 4; ++q) s += partial[q * 256 + t];
        float* ps = (float*)wpack;                   // reuse as 256-float scratch
        ps[t] = s;
        __syncthreads();
        for (int st = 128; st >= 1; st >>= 1) {
            if (t < st) ps[t] += ps[t + st];
            __syncthreads();
        }
        if (t == 0) {
            float mse = ps[0] / (float)NDTOT;
            out[NDTOT]     = 0.25f * mse;            // commitment_loss
            out[NDTOT + 1] = mse;                    // codebook_loss
        }
    }
}

// ---------- fallback fp32 path (round-1, correctness-proven) ----------
__global__ __launch_bounds__(64) void vq_init(float* out) {
    if (threadIdx.x == 0) { out[NDTOT] = 0.0f; out[NDTOT + 1] = 0.0f; }
}

__global__ __launch_bounds__(256, 4) void vq_main_fp32(const float* __restrict__ z,
                                                       const float* __restrict__ E,
                                                       float* __restrict__ out,
                                                       float* __restrict__ partial) {
    __shared__ float zs[64][65];
    __shared__ float e2s[KCB];
    __shared__ float wmin[4][64];
    __shared__ int   widx[4][64];
    __shared__ int   rowidx[64];
    __shared__ float wsum[4];

    const int t   = threadIdx.x;
    const int blk = blockIdx.x;
    const int n0  = blk << 6;
    const int bb  = n0 >> 12;
    const int hw0 = n0 & 4095;
    const float* zb = z + (size_t)bb * CCH * HWSZ + hw0;

    #pragma unroll
    for (int j = 0; j < 16; ++j) {
        int f = t + 256 * j;
        int c = f >> 6, i = f & 63;
        zs[c][i] = zb[(size_t)c * HWSZ + i];
    }
    for (int qq = t; qq < KCB; qq += 256) {
        const float4* ep = (const float4*)(E + (size_t)qq * 64);
        float s0 = 0.f;
        #pragma unroll
        for (int c4 = 0; c4 < 16; ++c4) {
            float4 a = ep[c4];
            s0 += a.x * a.x + a.y * a.y + a.z * a.z + a.w * a.w;
        }
        e2s[qq] = s0;
    }
    __syncthreads();

    const int i   = t & 63;
    const int wid = t >> 6;
    float zr[64];
    #pragma unroll
    for (int c = 0; c < 64; ++c) zr[c] = zs[c][i];

    float best = 3.4e38f;
    int   bi = 0;
    const int k0 = wid << 8;
    const float* Ew = E + (size_t)k0 * 64;
    for (int kk = 0; kk < 256; ++kk) {
        const float4* ek = (const float4*)(Ew + (size_t)kk * 64);
        float d0 = 0.f, d1 = 0.f, d2 = 0.f, d3 = 0.f;
        #pragma unroll
        for (int c4 = 0; c4 < 16; ++c4) {
            float4 a = ek[c4];
            d0 = fmaf(a.x, zr[4 * c4 + 0], d0);
            d1 = fmaf(a.y, zr[4 * c4 + 1], d1);
            d2 = fmaf(a.z, zr[4 * c4 + 2], d2);
            d3 = fmaf(a.w, zr[4 * c4 + 3], d3);
        }
        float dot  = (d0 + d1) + (d2 + d3);
        float dist = fmaf(-2.0f, dot, e2s[k0 + kk]);
        if (dist < best) { best = dist; bi = k0 + kk; }
    }
    wmin[wid][i] = best; widx[wid][i] = bi;
    __syncthreads();
    if (t < 64) {
        float m = wmin[0][t]; int ix = widx[0][t];
        #pragma unroll
        for (int w = 1; w < 4; ++w) {
            float v = wmin[w][t]; int x = widx[w][t];
            if (v < m) { m = v; ix = x; }
        }
        rowidx[t] = ix;
    }
    __syncthreads();

    float lsum = 0.f;
    const size_t base = (size_t)blk * 4096;
    float* oflat = out + base;
    #pragma unroll
    for (int j = 0; j < 16; ++j) {
        int f  = t + 256 * j;
        int nl = f >> 6, d = f & 63;
        int k  = rowidx[nl];
        float qv = E[(size_t)k * 64 + d];
        float zf = zs[d][nl];
        float df = qv - zf;
        lsum += df * df;
        oflat[f] = qv;
    }
    #pragma unroll
    for (int off = 32; off >= 1; off >>= 1) lsum += __shfl_down(lsum, off, 64);
    if (i == 0) wsum[wid] = lsum;
    __syncthreads();
    if (t == 0) {
        float s = (wsum[0] + wsum[1]) + (wsum[2] + wsum[3]);
        if (partial) partial[blk] = s;
        else         atomicAdd(&out[NDTOT + 1], s);
    }
}

__global__ __launch_bounds__(256) void vq_fin(const float* __restrict__ partial,
                                              float* __restrict__ out, int npart) {
    if (npart > 0) {
        __shared__ float ps[256];
        float s = 0.f;
        for (int qq = threadIdx.x; qq < npart; qq += 256) s += partial[qq];
        ps[threadIdx.x] = s;
        __syncthreads();
        for (int st = 128; st >= 1; st >>= 1) {
            if (threadIdx.x < st) ps[threadIdx.x] += ps[threadIdx.x + st];
            __syncthreads();
        }
        if (threadIdx.x == 0) {
            float mse = ps[0] / (float)NDTOT;
            out[NDTOT]     = 0.25f * mse;   // commitment_loss
            out[NDTOT + 1] = mse;           // codebook_loss
        }
    } else {
        if (threadIdx.x == 0) {
            float mse = out[NDTOT + 1] / (float)NDTOT;
            out[NDTOT]     = 0.25f * mse;
            out[NDTOT + 1] = mse;
        }
    }
}

extern "C" void kernel_launch(void* const* d_in, const int* in_sizes, int n_in,
                              void* d_out, int out_size, void* d_ws, size_t ws_size,
                              hipStream_t stream) {
    const float* z = (const float*)d_in[0];
    const float* E = (const float*)d_in[1];
    float* out = (float*)d_out;

    const size_t EBF_BYTES = (size_t)KCB * 64 * 2;                 // 131072
    const size_t HE2_OFF   = EBF_BYTES;                            // 4 KB
    const size_t PART_OFF  = EBF_BYTES + 4096;                     // 4 KB (1024 floats)
    const size_t CNT_OFF   = EBF_BYTES + 4096 + 4096;
    const size_t need      = CNT_OFF + 64;

    if (ws_size >= need) {
        unsigned* EbfU    = (unsigned*)d_ws;
        short*    Ebf     = (short*)d_ws;
        float*    he2b    = (float*)((char*)d_ws + HE2_OFF);
        float*    partial = (float*)((char*)d_ws + PART_OFF);
        unsigned* counter = (unsigned*)((char*)d_ws + CNT_OFF);
        hipLaunchKernelGGL(vq_prep, dim3(16), dim3(256), 0, stream, E, EbfU, he2b, counter);
        hipLaunchKernelGGL(vq_mfma, dim3(MBLK), dim3(256), 0, stream,
                           z, E, Ebf, he2b, out, partial, counter);
    } else {
        float* partial = (ws_size >= KCB * sizeof(float)) ? (float*)d_ws : nullptr;
        int npart = (partial != nullptr) ? KCB : 0;
        hipLaunchKernelGGL(vq_init, dim3(1), dim3(64), 0, stream, out);
        hipLaunchKernelGGL(vq_main_fp32, dim3(1024), dim3(256), 0, stream, z, E, out, partial);
        hipLaunchKernelGGL(vq_fin, dim3(1), dim3(256), 0, stream, partial, out, npart);
    }
}

// Round 12
// 176.905 us; speedup vs baseline: 1.1387x; 1.1243x over previous
//
#include <hip/hip_runtime.h>

// Problem constants (B=16, C=64, H=64, W=64, K=1024, D=64)
#define HWSZ   4096
#define CCH    64
#define KCB    1024
#define NROW   65536
#define NDTOT  4194304
#define MBLK   1024            // main-path blocks (64 rows each)

typedef __attribute__((ext_vector_type(8))) short short8;
typedef __attribute__((ext_vector_type(4))) float f32x4;

typedef const __attribute__((address_space(1))) unsigned gas_u32;
typedef __attribute__((address_space(3))) unsigned las_u32;

__device__ __forceinline__ unsigned short f2bf_rn(float x) {
    union { float f; unsigned u; } v; v.f = x;
    unsigned r = (v.u + 0x7fffu + ((v.u >> 16) & 1u)) >> 16;
    return (unsigned short)r;
}

// ---------- prep: 16 blocks, 4 threads/code: E -> swizzled bf16 + he2b + counter=0 ----------
__global__ __launch_bounds__(256) void vq_prep(const float* __restrict__ E,
                                               unsigned* __restrict__ Ebf,
                                               float* __restrict__ he2b,
                                               unsigned* __restrict__ counter) {
    const int t = threadIdx.x;
    if (blockIdx.x == 0 && t == 0) *counter = 0u;
    const int gid  = blockIdx.x * 256 + t;
    const int code = gid >> 2;           // 0..1023
    const int part = gid & 3;
    const float4* ep = (const float4*)(E + (size_t)code * 64 + part * 16);
    const unsigned sw = ((unsigned)code & 7u) << 2;   // T2 swizzle on dword index
    float s = 0.f;
    #pragma unroll
    for (int q = 0; q < 4; ++q) {
        float4 a = ep[q];
        s += a.x * a.x + a.y * a.y + a.z * a.z + a.w * a.w;
        unsigned lo = (unsigned)f2bf_rn(a.x) | ((unsigned)f2bf_rn(a.y) << 16);
        unsigned hi = (unsigned)f2bf_rn(a.z) | ((unsigned)f2bf_rn(a.w) << 16);
        unsigned base = (unsigned)code * 32 + part * 8 + q * 2;
        Ebf[base ^ sw]       = lo;       // (base+1)^sw == (base^sw)+1 (sw bits >= 2)
        Ebf[(base + 1) ^ sw] = hi;
    }
    s += __shfl_xor(s, 1, 64);
    s += __shfl_xor(s, 2, 64);
    if (part == 0) he2b[code] = 1.0f + 0.5f * s;
}

// ---------- main: 1024 blocks x 256 thr; block = 64 rows; wave = 64 rows x 256 codes ----------
// z AND codebook chunks staged via global_load_lds (zero staging VGPRs). A-frags built
// from LDS scalar reads (prevents the 64-hoisted-global-load VGPR peak that spilled
// r9/r10). Scan loop barrier-free with per-wave LDS buffers + counted vmcnt(4).
// r11 BUG FIX: z-slot decomposition is 16 slots/channel (slot>>4, slot&15, +s4*16B);
// r11's slot>>2/&3 read up to 4MB OOB -> memory fault.
__global__ __launch_bounds__(256, 2) void vq_mfma(const float* __restrict__ z,
                                                  const float* __restrict__ E,
                                                  const short* __restrict__ Ebf,
                                                  const float* __restrict__ he2g,
                                                  float* __restrict__ out,
                                                  float* __restrict__ partial,
                                                  unsigned* __restrict__ counter) {
    __shared__ short lbs[2][4][2048];      // per-wave double-buffered 4KB B-chunks (32 KB)
    __shared__ float zs[4096];             // z tile [c][i] linear: zs[c*64+i] (16 KB)
    __shared__ unsigned wpack[4][64];
    __shared__ int rowidx[64];
    __shared__ float wsum[4];
    __shared__ unsigned sflag;

    const int t   = threadIdx.x;           // 0..255
    const int blk = blockIdx.x;            // 0..1023
    const int n0  = blk << 6;              // 64 rows
    const int bb  = n0 >> 12;
    const int hw0 = n0 & 4095;
    const int wid = t >> 6, lane = t & 63, col = lane & 15, g = lane >> 4;
    const char* zwb = (const char*)(z + (size_t)bb * CCH * HWSZ + hw0);

    // ---- issue z stage: 64 ch x 256B rows = 1024 x 16B slots, 4 per thread (DMA) ----
    // slot s covers channel c = s>>4, bytes [s4*16, s4*16+16) of that channel's row.
    #pragma unroll
    for (int q = 0; q < 4; ++q) {
        int slot = q * 256 + t;            // wave dest = uniform base + lane*16  ✓
        int c = slot >> 4, s4 = slot & 15;
        __builtin_amdgcn_global_load_lds((gas_u32*)(zwb + (size_t)c * (HWSZ * 4) + s4 * 16),
                                         (las_u32*)((char*)zs + slot * 16), 16, 0, 0);
    }

    // wave's codebook quarter in (pre-swizzled) global Ebf: 256 codes = 32 KB, chunk = 4 KB
    const char* gq = (const char*)Ebf + (size_t)wid * 32768 + (size_t)lane * 16;
    // ---- issue B chunk 0 into buf 0 ----
    #pragma unroll
    for (int i = 0; i < 4; ++i)
        __builtin_amdgcn_global_load_lds((gas_u32*)(gq + i * 1024),
                                         (las_u32*)((char*)lbs[0][wid] + i * 1024), 16, 0, 0);

    // ---- bias prefetch: wave's 16 code-tiles (16 VGPR) ----
    float hvv[16];
    #pragma unroll
    for (int q = 0; q < 16; ++q) hvv[q] = he2g[wid * 256 + q * 16 + col];

    __syncthreads();   // drains all DMAs (z + chunk0) and publishes zs to all waves

    // ---- A-frags rt=4 + z^2 from LDS (scalar ds_reads -> no global-load VGPR peak) ----
    float z2 = 0.f;
    short8 af[4][2];
    #pragma unroll
    for (int rt = 0; rt < 4; ++rt) {
        const int i = rt * 16 + col;
        #pragma unroll
        for (int ch = 0; ch < 2; ++ch) {
            short8 a;
            #pragma unroll
            for (int j = 0; j < 8; ++j) {
                int c = ch * 32 + g * 8 + j;
                float v = zs[(c << 6) + i];
                z2 = fmaf(v, v, z2);
                union { float f; unsigned u; } uu; uu.f = v;
                a[j] = (short)((uu.u >> 16) ^ 0x8000u);   // -z, bf16 truncation
            }
            af[rt][ch] = a;
        }
    }

    float pk[4][4];
    #pragma unroll
    for (int rt = 0; rt < 4; ++rt)
        #pragma unroll
        for (int r = 0; r < 4; ++r) pk[rt][r] = 3.0e38f;

    const int swz = (col & 7) << 3;                  // swizzle in shorts (16B units)
    const int roA = (g * 8) ^ swz;
    const int roB = (32 + g * 8) ^ swz;

    // ---- 8 chunk steps, barrier-free; counted vmcnt keeps next chunk in flight ----
    #pragma unroll
    for (int c = 0; c < 8; ++c) {
        if (c < 7) {                                 // issue next chunk -> other buffer
            const char* gn = gq + (size_t)(c + 1) * 4096;
            char* ld = (char*)lbs[(c + 1) & 1][wid];
            #pragma unroll
            for (int i = 0; i < 4; ++i)
                __builtin_amdgcn_global_load_lds((gas_u32*)(gn + i * 1024),
                                                 (las_u32*)(ld + i * 1024), 16, 0, 0);
            asm volatile("s_waitcnt vmcnt(4)" ::: "memory");   // chunk c landed
        } else {
            asm volatile("s_waitcnt vmcnt(0)" ::: "memory");   // last chunk: drain
        }
        __builtin_amdgcn_sched_barrier(0);           // rule #18: pin reads after the wait

        const short* Lb = lbs[c & 1][wid];
        short8 b00 = *(const short8*)(Lb + (0 * 16 + col) * 64 + roA);
        short8 b01 = *(const short8*)(Lb + (0 * 16 + col) * 64 + roB);
        short8 b10 = *(const short8*)(Lb + (1 * 16 + col) * 64 + roA);
        short8 b11 = *(const short8*)(Lb + (1 * 16 + col) * 64 + roB);
        const unsigned code0 = (unsigned)(wid * 256 + c * 32 + col);
        const unsigned code1 = code0 + 16;
        const float h0 = hvv[c * 2 + 0], h1 = hvv[c * 2 + 1];
        f32x4 hv0 = {h0, h0, h0, h0};
        f32x4 hv1 = {h1, h1, h1, h1};
        #pragma unroll
        for (int rt = 0; rt < 4; ++rt) {
            f32x4 a0 = __builtin_amdgcn_mfma_f32_16x16x32_bf16(af[rt][0], b00, hv0, 0, 0, 0);
            a0 = __builtin_amdgcn_mfma_f32_16x16x32_bf16(af[rt][1], b01, a0, 0, 0, 0);
            f32x4 a1 = __builtin_amdgcn_mfma_f32_16x16x32_bf16(af[rt][0], b10, hv1, 0, 0, 0);
            a1 = __builtin_amdgcn_mfma_f32_16x16x32_bf16(af[rt][1], b11, a1, 0, 0, 0);
            #pragma unroll
            for (int r = 0; r < 4; ++r) {
                union { float f; unsigned u; } m0, m1;
                m0.f = a0[r]; m0.u = (m0.u & 0xFFFFFC00u) | code0;   // v_and_or_b32
                m1.f = a1[r]; m1.u = (m1.u & 0xFFFFFC00u) | code1;
                pk[rt][r] = fminf(fminf(pk[rt][r], m0.f), m1.f);     // v_min3_f32
            }
        }
    }

    // ---- butterfly min over 16 code-columns; publish per-wave row answers ----
    #pragma unroll
    for (int rt = 0; rt < 4; ++rt) {
        #pragma unroll
        for (int r = 0; r < 4; ++r) {
            float d = pk[rt][r];
            #pragma unroll
            for (int mask = 1; mask < 16; mask <<= 1)
                d = fminf(d, __shfl_xor(d, mask, 64));
            if (col == 0) {
                union { float f; unsigned u; } b; b.f = d;
                wpack[wid][rt * 16 + g * 4 + r] = b.u;
            }
        }
    }
    // z^2 wave reduce (identical across waves; wave 0's used)
    #pragma unroll
    for (int off = 32; off >= 1; off >>= 1) z2 += __shfl_down(z2, off, 64);
    if (lane == 0) wsum[wid] = z2;
    __syncthreads();

    if (t < 64) {   // combine 4 code-quarters; loss from winning scores
        unsigned u0 = wpack[0][t], u1 = wpack[1][t];
        unsigned u2 = wpack[2][t], u3 = wpack[3][t];
        unsigned m01 = u0 < u1 ? u0 : u1;
        unsigned m23 = u2 < u3 ? u2 : u3;
        unsigned m = m01 < m23 ? m01 : m23;
        rowidx[t] = (int)(m & 1023u);
        union { unsigned u; float f; } sc; sc.u = m & 0xFFFFFC00u;
        float scv = 2.0f * (sc.f - 1.0f);            // ||e||^2 - 2 z.e
        #pragma unroll
        for (int off = 32; off >= 1; off >>= 1) scv += __shfl_down(scv, off, 64);
        if (t == 0) partial[blk] = wsum[0] + scv;
    }
    __syncthreads();

    // ---- output = E rows (== z + (q - z) to 1 ulp), float4 coalesced ----
    const int d0i = (t & 15) * 4;
    const int r0  = t >> 4;                          // 0..15
    float* ob = out + (size_t)n0 * 64;
    #pragma unroll
    for (int jj = 0; jj < 4; ++jj) {
        int nl = r0 + 16 * jj;
        int k  = rowidx[nl];                         // uniform per 16-lane group
        float4 qv = *(const float4*)(E + (size_t)k * 64 + d0i);
        *(float4*)(ob + (size_t)nl * 64 + d0i) = qv;
    }

    // ---- last-block ticket: finalize losses (no separate fin launch) ----
    __threadfence();
    if (t == 0) sflag = (atomicAdd(counter, 1u) == (MBLK - 1)) ? 1u : 0u;
    __syncthreads();
    if (sflag) {
        __threadfence();
        float s = 0.f;
        #pragma unroll
        for (int q = 0; q < 4; ++q) s += partial[q * 256 + t];
        float* ps = (float*)wpack;                   // reuse as 256-float scratch
        ps[t] = s;
        __syncthreads();
        for (int st = 128; st >= 1; st >>= 1) {
            if (t < st) ps[t] += ps[t + st];
            __syncthreads();
        }
        if (t == 0) {
            float mse = ps[0] / (float)NDTOT;
            out[NDTOT]     = 0.25f * mse;            // commitment_loss
            out[NDTOT + 1] = mse;                    // codebook_loss
        }
    }
}

// ---------- fallback fp32 path (round-1, correctness-proven) ----------
__global__ __launch_bounds__(64) void vq_init(float* out) {
    if (threadIdx.x == 0) { out[NDTOT] = 0.0f; out[NDTOT + 1] = 0.0f; }
}

__global__ __launch_bounds__(256, 4) void vq_main_fp32(const float* __restrict__ z,
                                                       const float* __restrict__ E,
                                                       float* __restrict__ out,
                                                       float* __restrict__ partial) {
    __shared__ float zs[64][65];
    __shared__ float e2s[KCB];
    __shared__ float wmin[4][64];
    __shared__ int   widx[4][64];
    __shared__ int   rowidx[64];
    __shared__ float wsum[4];

    const int t   = threadIdx.x;
    const int blk = blockIdx.x;
    const int n0  = blk << 6;
    const int bb  = n0 >> 12;
    const int hw0 = n0 & 4095;
    const float* zb = z + (size_t)bb * CCH * HWSZ + hw0;

    #pragma unroll
    for (int j = 0; j < 16; ++j) {
        int f = t + 256 * j;
        int c = f >> 6, i = f & 63;
        zs[c][i] = zb[(size_t)c * HWSZ + i];
    }
    for (int qq = t; qq < KCB; qq += 256) {
        const float4* ep = (const float4*)(E + (size_t)qq * 64);
        float s0 = 0.f;
        #pragma unroll
        for (int c4 = 0; c4 < 16; ++c4) {
            float4 a = ep[c4];
            s0 += a.x * a.x + a.y * a.y + a.z * a.z + a.w * a.w;
        }
        e2s[qq] = s0;
    }
    __syncthreads();

    const int i   = t & 63;
    const int wid = t >> 6;
    float zr[64];
    #pragma unroll
    for (int c = 0; c < 64; ++c) zr[c] = zs[c][i];

    float best = 3.4e38f;
    int   bi = 0;
    const int k0 = wid << 8;
    const float* Ew = E + (size_t)k0 * 64;
    for (int kk = 0; kk < 256; ++kk) {
        const float4* ek = (const float4*)(Ew + (size_t)kk * 64);
        float d0 = 0.f, d1 = 0.f, d2 = 0.f, d3 = 0.f;
        #pragma unroll
        for (int c4 = 0; c4 < 16; ++c4) {
            float4 a = ek[c4];
            d0 = fmaf(a.x, zr[4 * c4 + 0], d0);
            d1 = fmaf(a.y, zr[4 * c4 + 1], d1);
            d2 = fmaf(a.z, zr[4 * c4 + 2], d2);
            d3 = fmaf(a.w, zr[4 * c4 + 3], d3);
        }
        float dot  = (d0 + d1) + (d2 + d3);
        float dist = fmaf(-2.0f, dot, e2s[k0 + kk]);
        if (dist < best) { best = dist; bi = k0 + kk; }
    }
    wmin[wid][i] = best; widx[wid][i] = bi;
    __syncthreads();
    if (t < 64) {
        float m = wmin[0][t]; int ix = widx[0][t];
        #pragma unroll
        for (int w = 1; w < 4; ++w) {
            float v = wmin[w][t]; int x = widx[w][t];
            if (v < m) { m = v; ix = x; }
        }
        rowidx[t] = ix;
    }
    __syncthreads();

    float lsum = 0.f;
    const size_t base = (size_t)blk * 4096;
    float* oflat = out + base;
    #pragma unroll
    for (int j = 0; j < 16; ++j) {
        int f  = t + 256 * j;
        int nl = f >> 6, d = f & 63;
        int k  = rowidx[nl];
        float qv = E[(size_t)k * 64 + d];
        float zf = zs[d][nl];
        float df = qv - zf;
        lsum += df * df;
        oflat[f] = qv;
    }
    #pragma unroll
    for (int off = 32; off >= 1; off >>= 1) lsum += __shfl_down(lsum, off, 64);
    if (i == 0) wsum[wid] = lsum;
    __syncthreads();
    if (t == 0) {
        float s = (wsum[0] + wsum[1]) + (wsum[2] + wsum[3]);
        if (partial) partial[blk] = s;
        else         atomicAdd(&out[NDTOT + 1], s);
    }
}

__global__ __launch_bounds__(256) void vq_fin(const float* __restrict__ partial,
                                              float* __restrict__ out, int npart) {
    if (npart > 0) {
        __shared__ float ps[256];
        float s = 0.f;
        for (int qq = threadIdx.x; qq < npart; qq += 256) s += partial[qq];
        ps[threadIdx.x] = s;
        __syncthreads();
        for (int st = 128; st >= 1; st >>= 1) {
            if (threadIdx.x < st) ps[threadIdx.x] += ps[threadIdx.x + st];
            __syncthreads();
        }
        if (threadIdx.x == 0) {
            float mse = ps[0] / (float)NDTOT;
            out[NDTOT]     = 0.25f * mse;   // commitment_loss
            out[NDTOT + 1] = mse;           // codebook_loss
        }
    } else {
        if (threadIdx.x == 0) {
            float mse = out[NDTOT + 1] / (float)NDTOT;
            out[NDTOT]     = 0.25f * mse;
            out[NDTOT + 1] = mse;
        }
    }
}

extern "C" void kernel_launch(void* const* d_in, const int* in_sizes, int n_in,
                              void* d_out, int out_size, void* d_ws, size_t ws_size,
                              hipStream_t stream) {
    const float* z = (const float*)d_in[0];
    const float* E = (const float*)d_in[1];
    float* out = (float*)d_out;

    const size_t EBF_BYTES = (size_t)KCB * 64 * 2;                 // 131072
    const size_t HE2_OFF   = EBF_BYTES;                            // 4 KB
    const size_t PART_OFF  = EBF_BYTES + 4096;                     // 4 KB (1024 floats)
    const size_t CNT_OFF   = EBF_BYTES + 4096 + 4096;
    const size_t need      = CNT_OFF + 64;

    if (ws_size >= need) {
        unsigned* EbfU    = (unsigned*)d_ws;
        short*    Ebf     = (short*)d_ws;
        float*    he2b    = (float*)((char*)d_ws + HE2_OFF);
        float*    partial = (float*)((char*)d_ws + PART_OFF);
        unsigned* counter = (unsigned*)((char*)d_ws + CNT_OFF);
        hipLaunchKernelGGL(vq_prep, dim3(16), dim3(256), 0, stream, E, EbfU, he2b, counter);
        hipLaunchKernelGGL(vq_mfma, dim3(MBLK), dim3(256), 0, stream,
                           z, E, Ebf, he2b, out, partial, counter);
    } else {
        float* partial = (ws_size >= KCB * sizeof(float)) ? (float*)d_ws : nullptr;
        int npart = (partial != nullptr) ? KCB : 0;
        hipLaunchKernelGGL(vq_init, dim3(1), dim3(64), 0, stream, out);
        hipLaunchKernelGGL(vq_main_fp32, dim3(1024), dim3(256), 0, stream, z, E, out, partial);
        hipLaunchKernelGGL(vq_fin, dim3(1), dim3(256), 0, stream, partial, out, npart);
    }
}

// Round 13
// 84.231 us; speedup vs baseline: 2.3916x; 2.1002x over previous
//
#include <hip/hip_runtime.h>

// Problem constants (B=16, C=64, H=64, W=64, K=1024, D=64)
#define HWSZ   4096
#define CCH    64
#define KCB    1024
#define NROW   65536
#define NDTOT  4194304
#define MBLK   512             // main-path blocks
#define BROWS  128             // rows per block
#define WROWS  32              // rows per wave
#define NCHUNK 16              // codebook chunks
#define CHCODES 64             // codes per chunk (8 KB bf16)

typedef __attribute__((ext_vector_type(8))) short short8;
typedef __attribute__((ext_vector_type(4))) float f32x4;

__device__ __forceinline__ unsigned short f2bf_rn(float x) {
    union { float f; unsigned u; } v; v.f = x;
    unsigned r = (v.u + 0x7fffu + ((v.u >> 16) & 1u)) >> 16;
    return (unsigned short)r;
}

// ---------- prep: 16 blocks, 4 threads/code: E -> swizzled bf16 + he2b + counter=0 ----------
__global__ __launch_bounds__(256) void vq_prep(const float* __restrict__ E,
                                               unsigned* __restrict__ Ebf,
                                               float* __restrict__ he2b,
                                               unsigned* __restrict__ counter) {
    const int t = threadIdx.x;
    if (blockIdx.x == 0 && t == 0) *counter = 0u;
    const int gid  = blockIdx.x * 256 + t;
    const int code = gid >> 2;           // 0..1023
    const int part = gid & 3;
    const float4* ep = (const float4*)(E + (size_t)code * 64 + part * 16);
    const unsigned sw = ((unsigned)code & 7u) << 2;   // T2 swizzle on dword index
    float s = 0.f;
    #pragma unroll
    for (int q = 0; q < 4; ++q) {
        float4 a = ep[q];
        s += a.x * a.x + a.y * a.y + a.z * a.z + a.w * a.w;
        unsigned lo = (unsigned)f2bf_rn(a.x) | ((unsigned)f2bf_rn(a.y) << 16);
        unsigned hi = (unsigned)f2bf_rn(a.z) | ((unsigned)f2bf_rn(a.w) << 16);
        unsigned base = (unsigned)code * 32 + part * 8 + q * 2;
        Ebf[base ^ sw]       = lo;       // (base+1)^sw == (base^sw)+1 (sw bits >= 2)
        Ebf[(base + 1) ^ sw] = hi;
    }
    s += __shfl_xor(s, 1, 64);
    s += __shfl_xor(s, 2, 64);
    if (part == 0) he2b[code] = 1.0f + 0.5f * s;
}

// ---------- main: r8's proven 31-us kernel + last-block ticket finalize ----------
// 512 blocks x 256 thr; block = 128 rows; wave = autonomous 32 rows x all 1024 codes.
// Codebook streamed through 16 double-buffered 8KB LDS chunks (reg-staged,
// issue-early/write-late, one barrier per chunk). A-frags + sum(z^2) direct from
// global. Loss derived from packed winning scores. Register demand ~85 < 128 cap.
__global__ __launch_bounds__(256, 2) void vq_mfma(const float* __restrict__ z,
                                                  const float* __restrict__ E,
                                                  const short* __restrict__ Ebf,
                                                  const float* __restrict__ he2g,
                                                  float* __restrict__ out,
                                                  float* __restrict__ partial,
                                                  unsigned* __restrict__ counter) {
    __shared__ short lbs[2][4096];     // 2 x 8 KB chunk buffers (swizzled image of Ebf)
    __shared__ float wsum[4];
    __shared__ unsigned sflag;

    const int t   = threadIdx.x;       // 0..255
    const int blk = blockIdx.x;        // 0..511
    const int n0  = blk * BROWS;
    const int bb  = n0 >> 12;
    const int wid = t >> 6, lane = t & 63, col = lane & 15, g = lane >> 4;
    const int hwb = (n0 & 4095) + wid * WROWS;      // wave's hw base (within one image)
    const float* zw = z + (size_t)bb * CCH * HWSZ + hwb;

    // ---- A-frags (2 rt x 2 ch) + z^2 partial, direct from global (no LDS, no barrier) ----
    float z2 = 0.f;
    short8 af[2][2];
    #pragma unroll
    for (int rt = 0; rt < 2; ++rt) {
        #pragma unroll
        for (int ch = 0; ch < 2; ++ch) {
            short8 a;
            #pragma unroll
            for (int j = 0; j < 8; ++j) {
                int c = ch * 32 + g * 8 + j;
                float v = zw[(size_t)c * HWSZ + rt * 16 + col];
                z2 = fmaf(v, v, z2);
                union { float f; unsigned u; } uu; uu.f = v;
                a[j] = (short)((uu.u >> 16) ^ 0x8000u);   // -z, bf16 truncation
            }
            af[rt][ch] = a;
        }
    }

    // ---- prologue: stage chunk 0 (32 B/thread) + he2 for chunk 0 ----
    const short8* gB = (const short8*)Ebf;          // 16 B units; swizzle rides along
    short8 sA = gB[t * 2];
    short8 sB = gB[t * 2 + 1];
    float hcur[4];
    #pragma unroll
    for (int q = 0; q < 4; ++q) hcur[q] = he2g[q * 16 + col];
    ((short8*)lbs[0])[t * 2]     = sA;
    ((short8*)lbs[0])[t * 2 + 1] = sB;
    __syncthreads();

    float pk[2][4];
    #pragma unroll
    for (int rt = 0; rt < 2; ++rt)
        #pragma unroll
        for (int r = 0; r < 4; ++r) pk[rt][r] = 3.0e38f;

    // per-lane swizzled LDS read offsets (shorts)
    const int swz = (col & 7) << 3;
    const int ro0 = col * 64 + ((g * 8) ^ swz);
    const int ro1 = col * 64 + ((32 + g * 8) ^ swz);

    #pragma unroll 2
    for (int c = 0; c < NCHUNK; ++c) {
        // T14 issue-early: next chunk's loads start before this chunk's compute
        short8 nA, nB; float hn[4];
        if (c < NCHUNK - 1) {
            nA = gB[(size_t)(c + 1) * 512 + t * 2];
            nB = gB[(size_t)(c + 1) * 512 + t * 2 + 1];
            #pragma unroll
            for (int q = 0; q < 4; ++q) hn[q] = he2g[(c + 1) * 64 + q * 16 + col];
        }

        const short* Lb = lbs[c & 1];
        #pragma unroll
        for (int cp = 0; cp < 2; ++cp) {            // ct pairs -> min3 fusion
            const int ct0 = cp * 2, ct1 = cp * 2 + 1;
            short8 b00 = *(const short8*)(Lb + ct0 * 1024 + ro0);
            short8 b01 = *(const short8*)(Lb + ct0 * 1024 + ro1);
            short8 b10 = *(const short8*)(Lb + ct1 * 1024 + ro0);
            short8 b11 = *(const short8*)(Lb + ct1 * 1024 + ro1);
            const unsigned code0 = (unsigned)(c * 64 + ct0 * 16 + col);
            const unsigned code1 = code0 + 16;
            f32x4 hv0 = {hcur[ct0], hcur[ct0], hcur[ct0], hcur[ct0]};
            f32x4 hv1 = {hcur[ct1], hcur[ct1], hcur[ct1], hcur[ct1]};
            #pragma unroll
            for (int rt = 0; rt < 2; ++rt) {
                f32x4 a0 = __builtin_amdgcn_mfma_f32_16x16x32_bf16(af[rt][0], b00, hv0, 0, 0, 0);
                a0 = __builtin_amdgcn_mfma_f32_16x16x32_bf16(af[rt][1], b01, a0, 0, 0, 0);
                f32x4 a1 = __builtin_amdgcn_mfma_f32_16x16x32_bf16(af[rt][0], b10, hv1, 0, 0, 0);
                a1 = __builtin_amdgcn_mfma_f32_16x16x32_bf16(af[rt][1], b11, a1, 0, 0, 0);
                #pragma unroll
                for (int r = 0; r < 4; ++r) {
                    union { float f; unsigned u; } m0, m1;
                    m0.f = a0[r]; m0.u = (m0.u & 0xFFFFFC00u) | code0;  // v_and_or_b32
                    m1.f = a1[r]; m1.u = (m1.u & 0xFFFFFC00u) | code1;
                    pk[rt][r] = fminf(fminf(pk[rt][r], m0.f), m1.f);    // -> v_min3_f32
                }
            }
        }

        // T14 write-late: land next chunk after compute; barrier closes the chunk
        if (c < NCHUNK - 1) {
            short* Ld = (short*)lbs[(c & 1) ^ 1];
            ((short8*)Ld)[t * 2]     = nA;
            ((short8*)Ld)[t * 2 + 1] = nB;
            #pragma unroll
            for (int q = 0; q < 4; ++q) hcur[q] = hn[q];
        }
        __syncthreads();
    }

    // ---- butterfly min over 16 code-columns (all lanes end with row's answer) ----
    #pragma unroll
    for (int rt = 0; rt < 2; ++rt) {
        #pragma unroll
        for (int r = 0; r < 4; ++r) {
            float d = pk[rt][r];
            #pragma unroll
            for (int mask = 1; mask < 16; mask <<= 1)
                d = fminf(d, __shfl_xor(d, mask, 64));
            pk[rt][r] = d;
        }
    }

    // ---- epilogue: output = E rows (k in-register), loss from scores ----
    float lsum = z2;
    const int rowbase = n0 + wid * WROWS;
    #pragma unroll
    for (int rt = 0; rt < 2; ++rt) {
        #pragma unroll
        for (int r = 0; r < 4; ++r) {
            union { float f; unsigned u; } b; b.f = pk[rt][r];
            unsigned kk = b.u & 1023u;
            if (col == 0) {                              // count each row's score once
                union { unsigned u; float f; } sc; sc.u = b.u & 0xFFFFFC00u;
                lsum += 2.0f * (sc.f - 1.0f);            // ||e||^2 - 2 z.e
            }
            int row = rt * 16 + g * 4 + r;
            float4 qv = *(const float4*)(E + (size_t)kk * 64 + col * 4);
            *(float4*)(out + ((size_t)(rowbase + row)) * 64 + col * 4) = qv;
        }
    }

    #pragma unroll
    for (int off = 32; off >= 1; off >>= 1) lsum += __shfl_down(lsum, off, 64);
    if (lane == 0) wsum[wid] = lsum;
    __syncthreads();
    if (t == 0) partial[blk] = (wsum[0] + wsum[1]) + (wsum[2] + wsum[3]);

    // ---- last-block ticket: finalize losses (replaces the vq_fin launch) ----
    __threadfence();
    if (t == 0) sflag = (atomicAdd(counter, 1u) == (MBLK - 1)) ? 1u : 0u;
    __syncthreads();
    if (sflag) {
        __threadfence();
        float s = partial[t] + partial[256 + t];         // 512 partials
        float* ps = (float*)lbs;                         // reuse chunk buffer as scratch
        ps[t] = s;
        __syncthreads();
        for (int st = 128; st >= 1; st >>= 1) {
            if (t < st) ps[t] += ps[t + st];
            __syncthreads();
        }
        if (t == 0) {
            float mse = ps[0] / (float)NDTOT;
            out[NDTOT]     = 0.25f * mse;                // commitment_loss
            out[NDTOT + 1] = mse;                        // codebook_loss
        }
    }
}

// ---------- fallback fp32 path (round-1, correctness-proven) ----------
__global__ __launch_bounds__(64) void vq_init(float* out) {
    if (threadIdx.x == 0) { out[NDTOT] = 0.0f; out[NDTOT + 1] = 0.0f; }
}

__global__ __launch_bounds__(256, 4) void vq_main_fp32(const float* __restrict__ z,
                                                       const float* __restrict__ E,
                                                       float* __restrict__ out,
                                                       float* __restrict__ partial) {
    __shared__ float zs[64][65];
    __shared__ float e2s[KCB];
    __shared__ float wmin[4][64];
    __shared__ int   widx[4][64];
    __shared__ int   rowidx[64];
    __shared__ float wsum[4];

    const int t   = threadIdx.x;
    const int blk = blockIdx.x;
    const int n0  = blk << 6;
    const int bb  = n0 >> 12;
    const int hw0 = n0 & 4095;
    const float* zb = z + (size_t)bb * CCH * HWSZ + hw0;

    #pragma unroll
    for (int j = 0; j < 16; ++j) {
        int f = t + 256 * j;
        int c = f >> 6, i = f & 63;
        zs[c][i] = zb[(size_t)c * HWSZ + i];
    }
    for (int qq = t; qq < KCB; qq += 256) {
        const float4* ep = (const float4*)(E + (size_t)qq * 64);
        float s0 = 0.f;
        #pragma unroll
        for (int c4 = 0; c4 < 16; ++c4) {
            float4 a = ep[c4];
            s0 += a.x * a.x + a.y * a.y + a.z * a.z + a.w * a.w;
        }
        e2s[qq] = s0;
    }
    __syncthreads();

    const int i   = t & 63;
    const int wid = t >> 6;
    float zr[64];
    #pragma unroll
    for (int c = 0; c < 64; ++c) zr[c] = zs[c][i];

    float best = 3.4e38f;
    int   bi = 0;
    const int k0 = wid << 8;
    const float* Ew = E + (size_t)k0 * 64;
    for (int kk = 0; kk < 256; ++kk) {
        const float4* ek = (const float4*)(Ew + (size_t)kk * 64);
        float d0 = 0.f, d1 = 0.f, d2 = 0.f, d3 = 0.f;
        #pragma unroll
        for (int c4 = 0; c4 < 16; ++c4) {
            float4 a = ek[c4];
            d0 = fmaf(a.x, zr[4 * c4 + 0], d0);
            d1 = fmaf(a.y, zr[4 * c4 + 1], d1);
            d2 = fmaf(a.z, zr[4 * c4 + 2], d2);
            d3 = fmaf(a.w, zr[4 * c4 + 3], d3);
        }
        float dot  = (d0 + d1) + (d2 + d3);
        float dist = fmaf(-2.0f, dot, e2s[k0 + kk]);
        if (dist < best) { best = dist; bi = k0 + kk; }
    }
    wmin[wid][i] = best; widx[wid][i] = bi;
    __syncthreads();
    if (t < 64) {
        float m = wmin[0][t]; int ix = widx[0][t];
        #pragma unroll
        for (int w = 1; w < 4; ++w) {
            float v = wmin[w][t]; int x = widx[w][t];
            if (v < m) { m = v; ix = x; }
        }
        rowidx[t] = ix;
    }
    __syncthreads();

    float lsum = 0.f;
    const size_t base = (size_t)blk * 4096;
    float* oflat = out + base;
    #pragma unroll
    for (int j = 0; j < 16; ++j) {
        int f  = t + 256 * j;
        int nl = f >> 6, d = f & 63;
        int k  = rowidx[nl];
        float qv = E[(size_t)k * 64 + d];
        float zf = zs[d][nl];
        float df = qv - zf;
        lsum += df * df;
        oflat[f] = qv;
    }
    #pragma unroll
    for (int off = 32; off >= 1; off >>= 1) lsum += __shfl_down(lsum, off, 64);
    if (i == 0) wsum[wid] = lsum;
    __syncthreads();
    if (t == 0) {
        float s = (wsum[0] + wsum[1]) + (wsum[2] + wsum[3]);
        if (partial) partial[blk] = s;
        else         atomicAdd(&out[NDTOT + 1], s);
    }
}

__global__ __launch_bounds__(256) void vq_fin(const float* __restrict__ partial,
                                              float* __restrict__ out, int npart) {
    if (npart > 0) {
        __shared__ float ps[256];
        float s = 0.f;
        for (int qq = threadIdx.x; qq < npart; qq += 256) s += partial[qq];
        ps[threadIdx.x] = s;
        __syncthreads();
        for (int st = 128; st >= 1; st >>= 1) {
            if (threadIdx.x < st) ps[threadIdx.x] += ps[threadIdx.x + st];
            __syncthreads();
        }
        if (threadIdx.x == 0) {
            float mse = ps[0] / (float)NDTOT;
            out[NDTOT]     = 0.25f * mse;   // commitment_loss
            out[NDTOT + 1] = mse;           // codebook_loss
        }
    } else {
        if (threadIdx.x == 0) {
            float mse = out[NDTOT + 1] / (float)NDTOT;
            out[NDTOT]     = 0.25f * mse;
            out[NDTOT + 1] = mse;
        }
    }
}

extern "C" void kernel_launch(void* const* d_in, const int* in_sizes, int n_in,
                              void* d_out, int out_size, void* d_ws, size_t ws_size,
                              hipStream_t stream) {
    const float* z = (const float*)d_in[0];
    const float* E = (const float*)d_in[1];
    float* out = (float*)d_out;

    const size_t EBF_BYTES = (size_t)KCB * 64 * 2;                 // 131072
    const size_t HE2_OFF   = EBF_BYTES;                            // 4 KB
    const size_t PART_OFF  = EBF_BYTES + 4096;                     // 2 KB used (512 floats)
    const size_t CNT_OFF   = EBF_BYTES + 4096 + 4096;
    const size_t need      = CNT_OFF + 64;

    if (ws_size >= need) {
        unsigned* EbfU    = (unsigned*)d_ws;
        short*    Ebf     = (short*)d_ws;
        float*    he2b    = (float*)((char*)d_ws + HE2_OFF);
        float*    partial = (float*)((char*)d_ws + PART_OFF);
        unsigned* counter = (unsigned*)((char*)d_ws + CNT_OFF);
        hipLaunchKernelGGL(vq_prep, dim3(16), dim3(256), 0, stream, E, EbfU, he2b, counter);
        hipLaunchKernelGGL(vq_mfma, dim3(MBLK), dim3(256), 0, stream,
                           z, E, Ebf, he2b, out, partial, counter);
    } else {
        float* partial = (ws_size >= KCB * sizeof(float)) ? (float*)d_ws : nullptr;
        int npart = (partial != nullptr) ? KCB : 0;
        hipLaunchKernelGGL(vq_init, dim3(1), dim3(64), 0, stream, out);
        hipLaunchKernelGGL(vq_main_fp32, dim3(1024), dim3(256), 0, stream, z, E, out, partial);
        hipLaunchKernelGGL(vq_fin, dim3(1), dim3(256), 0, stream, partial, out, npart);
    }
}

// Round 14
// 30.876 us; speedup vs baseline: 6.5242x; 2.7280x over previous
//
#include <hip/hip_runtime.h>

// Problem constants (B=16, C=64, H=64, W=64, K=1024, D=64)
#define HWSZ   4096
#define CCH    64
#define KCB    1024
#define NROW   65536
#define NDTOT  4194304
#define MBLK   512             // main-path blocks
#define BROWS  128             // rows per block
#define WROWS  32              // rows per wave
#define NCHUNK 8               // codebook chunks  (v14: 16 -> 8)
#define CHCODES 128            // codes per chunk (16 KB bf16)

typedef __attribute__((ext_vector_type(8))) short short8;
typedef __attribute__((ext_vector_type(4))) float f32x4;

__device__ __forceinline__ unsigned short f2bf_rn(float x) {
    union { float f; unsigned u; } v; v.f = x;
    unsigned r = (v.u + 0x7fffu + ((v.u >> 16) & 1u)) >> 16;
    return (unsigned short)r;
}

// ---------- prep: E -> bf16 rows (PRE-SWIZZLED: dword ^ ((k&7)<<2)) + he2b ----------
__global__ __launch_bounds__(256) void vq_prep(const float* __restrict__ E,
                                               unsigned* __restrict__ Ebf,
                                               float* __restrict__ he2b) {
    int k = blockIdx.x * 256 + threadIdx.x;   // 0..1023
    const float4* ep = (const float4*)(E + (size_t)k * 64);
    float s = 0.f;
    const unsigned sw = ((unsigned)k & 7u) << 2;   // T2 swizzle on dword index
    #pragma unroll
    for (int c4 = 0; c4 < 16; ++c4) {
        float4 a = ep[c4];
        s += a.x * a.x + a.y * a.y + a.z * a.z + a.w * a.w;
        unsigned lo = (unsigned)f2bf_rn(a.x) | ((unsigned)f2bf_rn(a.y) << 16);
        unsigned hi = (unsigned)f2bf_rn(a.z) | ((unsigned)f2bf_rn(a.w) << 16);
        unsigned base = (unsigned)k * 32 + 2 * c4;
        Ebf[base ^ sw]       = lo;     // (base+1)^sw == (base^sw)+1 (sw bits >= 2)
        Ebf[(base + 1) ^ sw] = hi;
    }
    he2b[k] = 1.0f + 0.5f * s;
}

// ---------- main: v8 structure, 8 x 16KB chunks (halved barrier count) ----------
// 512 blocks x 256 thr; block = 128 rows; wave = autonomous 32 rows x all 1024 codes.
// Codebook streamed through double-buffered LDS chunks (reg-staged, issue-early/
// write-late, ONE barrier per chunk). A-frags + sum(z^2) direct from global.
// Loss derived from packed winning scores. NO fences/tickets in-kernel (r13 lesson:
// __threadfence per block poisons L2 codebook residency -> 3x slowdown).
__global__ __launch_bounds__(256, 2) void vq_mfma(const float* __restrict__ z,
                                                  const float* __restrict__ E,
                                                  const short* __restrict__ Ebf,
                                                  const float* __restrict__ he2g,
                                                  float* __restrict__ out,
                                                  float* __restrict__ partial) {
    __shared__ short lbs[2][8192];     // 2 x 16 KB chunk buffers (swizzled image of Ebf)
    __shared__ float wsum[4];

    const int t   = threadIdx.x;       // 0..255
    const int blk = blockIdx.x;        // 0..511
    const int n0  = blk * BROWS;
    const int bb  = n0 >> 12;
    const int wid = t >> 6, lane = t & 63, col = lane & 15, g = lane >> 4;
    const int hwb = (n0 & 4095) + wid * WROWS;      // wave's hw base (within one image)
    const float* zw = z + (size_t)bb * CCH * HWSZ + hwb;

    // ---- A-frags (2 rt x 2 ch) + z^2 partial, direct from global ----
    float z2 = 0.f;
    short8 af[2][2];
    #pragma unroll
    for (int rt = 0; rt < 2; ++rt) {
        #pragma unroll
        for (int ch = 0; ch < 2; ++ch) {
            short8 a;
            #pragma unroll
            for (int j = 0; j < 8; ++j) {
                int c = ch * 32 + g * 8 + j;
                float v = zw[(size_t)c * HWSZ + rt * 16 + col];
                z2 = fmaf(v, v, z2);
                union { float f; unsigned u; } uu; uu.f = v;
                a[j] = (short)((uu.u >> 16) ^ 0x8000u);   // -z, bf16 truncation
            }
            af[rt][ch] = a;
        }
    }

    // ---- prologue: stage chunk 0 (64 B/thread) + he2 for chunk 0 ----
    const short8* gB = (const short8*)Ebf;          // 16 B units; swizzle rides along
    short8 sA = gB[0 * 256 + t];
    short8 sB = gB[1 * 256 + t];
    short8 sC = gB[2 * 256 + t];
    short8 sD = gB[3 * 256 + t];
    float hcur[8];
    #pragma unroll
    for (int q = 0; q < 8; ++q) hcur[q] = he2g[q * 16 + col];
    ((short8*)lbs[0])[0 * 256 + t] = sA;
    ((short8*)lbs[0])[1 * 256 + t] = sB;
    ((short8*)lbs[0])[2 * 256 + t] = sC;
    ((short8*)lbs[0])[3 * 256 + t] = sD;
    __syncthreads();

    float pk[2][4];
    #pragma unroll
    for (int rt = 0; rt < 2; ++rt)
        #pragma unroll
        for (int r = 0; r < 4; ++r) pk[rt][r] = 3.0e38f;

    // per-lane swizzled LDS read offsets (shorts)
    const int swz = (col & 7) << 3;
    const int ro0 = col * 64 + ((g * 8) ^ swz);
    const int ro1 = col * 64 + ((32 + g * 8) ^ swz);

    #pragma unroll 2
    for (int c = 0; c < NCHUNK; ++c) {
        // issue-early: next chunk's loads start before this chunk's compute
        short8 nA, nB, nC, nD; float hn[8];
        if (c < NCHUNK - 1) {
            const size_t nb = (size_t)(c + 1) * 1024;
            nA = gB[nb + 0 * 256 + t];
            nB = gB[nb + 1 * 256 + t];
            nC = gB[nb + 2 * 256 + t];
            nD = gB[nb + 3 * 256 + t];
            #pragma unroll
            for (int q = 0; q < 8; ++q) hn[q] = he2g[(c + 1) * 128 + q * 16 + col];
        }

        const short* Lb = lbs[c & 1];
        #pragma unroll
        for (int cp = 0; cp < 4; ++cp) {            // ct pairs -> min3 fusion
            const int ct0 = cp * 2, ct1 = cp * 2 + 1;
            short8 b00 = *(const short8*)(Lb + (ct0 * 16 + col) * 64 + ((g * 8) ^ swz) - col * 64 + col * 64);
            b00 = *(const short8*)(Lb + ct0 * 1024 + ro0);
            short8 b01 = *(const short8*)(Lb + ct0 * 1024 + ro1);
            short8 b10 = *(const short8*)(Lb + ct1 * 1024 + ro0);
            short8 b11 = *(const short8*)(Lb + ct1 * 1024 + ro1);
            const unsigned code0 = (unsigned)(c * 128 + ct0 * 16 + col);
            const unsigned code1 = code0 + 16;
            f32x4 hv0 = {hcur[ct0], hcur[ct0], hcur[ct0], hcur[ct0]};
            f32x4 hv1 = {hcur[ct1], hcur[ct1], hcur[ct1], hcur[ct1]};
            #pragma unroll
            for (int rt = 0; rt < 2; ++rt) {
                f32x4 a0 = __builtin_amdgcn_mfma_f32_16x16x32_bf16(af[rt][0], b00, hv0, 0, 0, 0);
                a0 = __builtin_amdgcn_mfma_f32_16x16x32_bf16(af[rt][1], b01, a0, 0, 0, 0);
                f32x4 a1 = __builtin_amdgcn_mfma_f32_16x16x32_bf16(af[rt][0], b10, hv1, 0, 0, 0);
                a1 = __builtin_amdgcn_mfma_f32_16x16x32_bf16(af[rt][1], b11, a1, 0, 0, 0);
                #pragma unroll
                for (int r = 0; r < 4; ++r) {
                    union { float f; unsigned u; } m0, m1;
                    m0.f = a0[r]; m0.u = (m0.u & 0xFFFFFC00u) | code0;  // v_and_or_b32
                    m1.f = a1[r]; m1.u = (m1.u & 0xFFFFFC00u) | code1;
                    pk[rt][r] = fminf(fminf(pk[rt][r], m0.f), m1.f);    // -> v_min3_f32
                }
            }
        }

        // write-late: land next chunk after compute; barrier closes the chunk
        if (c < NCHUNK - 1) {
            short8* Ld = (short8*)lbs[(c & 1) ^ 1];
            Ld[0 * 256 + t] = nA;
            Ld[1 * 256 + t] = nB;
            Ld[2 * 256 + t] = nC;
            Ld[3 * 256 + t] = nD;
            #pragma unroll
            for (int q = 0; q < 8; ++q) hcur[q] = hn[q];
        }
        __syncthreads();
    }

    // ---- butterfly min over 16 code-columns (all lanes end with row's answer) ----
    #pragma unroll
    for (int rt = 0; rt < 2; ++rt) {
        #pragma unroll
        for (int r = 0; r < 4; ++r) {
            float d = pk[rt][r];
            #pragma unroll
            for (int mask = 1; mask < 16; mask <<= 1)
                d = fminf(d, __shfl_xor(d, mask, 64));
            pk[rt][r] = d;
        }
    }

    // ---- epilogue: output = E rows (k in-register), loss from scores ----
    float lsum = z2;
    const int rowbase = n0 + wid * WROWS;
    #pragma unroll
    for (int rt = 0; rt < 2; ++rt) {
        #pragma unroll
        for (int r = 0; r < 4; ++r) {
            union { float f; unsigned u; } b; b.f = pk[rt][r];
            unsigned kk = b.u & 1023u;
            if (col == 0) {                              // count each row's score once
                union { unsigned u; float f; } sc; sc.u = b.u & 0xFFFFFC00u;
                lsum += 2.0f * (sc.f - 1.0f);            // ||e||^2 - 2 z.e
            }
            int row = rt * 16 + g * 4 + r;
            float4 qv = *(const float4*)(E + (size_t)kk * 64 + col * 4);
            *(float4*)(out + ((size_t)(rowbase + row)) * 64 + col * 4) = qv;
        }
    }

    #pragma unroll
    for (int off = 32; off >= 1; off >>= 1) lsum += __shfl_down(lsum, off, 64);
    if (lane == 0) wsum[wid] = lsum;
    __syncthreads();
    if (t == 0) partial[blk] = (wsum[0] + wsum[1]) + (wsum[2] + wsum[3]);
}

// ---------- fallback fp32 path (round-1, correctness-proven) ----------
__global__ __launch_bounds__(64) void vq_init(float* out) {
    if (threadIdx.x == 0) { out[NDTOT] = 0.0f; out[NDTOT + 1] = 0.0f; }
}

__global__ __launch_bounds__(256, 4) void vq_main_fp32(const float* __restrict__ z,
                                                       const float* __restrict__ E,
                                                       float* __restrict__ out,
                                                       float* __restrict__ partial) {
    __shared__ float zs[64][65];
    __shared__ float e2s[KCB];
    __shared__ float wmin[4][64];
    __shared__ int   widx[4][64];
    __shared__ int   rowidx[64];
    __shared__ float wsum[4];

    const int t   = threadIdx.x;
    const int blk = blockIdx.x;
    const int n0  = blk << 6;
    const int bb  = n0 >> 12;
    const int hw0 = n0 & 4095;
    const float* zb = z + (size_t)bb * CCH * HWSZ + hw0;

    #pragma unroll
    for (int j = 0; j < 16; ++j) {
        int f = t + 256 * j;
        int c = f >> 6, i = f & 63;
        zs[c][i] = zb[(size_t)c * HWSZ + i];
    }
    for (int qq = t; qq < KCB; qq += 256) {
        const float4* ep = (const float4*)(E + (size_t)qq * 64);
        float s0 = 0.f;
        #pragma unroll
        for (int c4 = 0; c4 < 16; ++c4) {
            float4 a = ep[c4];
            s0 += a.x * a.x + a.y * a.y + a.z * a.z + a.w * a.w;
        }
        e2s[qq] = s0;
    }
    __syncthreads();

    const int i   = t & 63;
    const int wid = t >> 6;
    float zr[64];
    #pragma unroll
    for (int c = 0; c < 64; ++c) zr[c] = zs[c][i];

    float best = 3.4e38f;
    int   bi = 0;
    const int k0 = wid << 8;
    const float* Ew = E + (size_t)k0 * 64;
    for (int kk = 0; kk < 256; ++kk) {
        const float4* ek = (const float4*)(Ew + (size_t)kk * 64);
        float d0 = 0.f, d1 = 0.f, d2 = 0.f, d3 = 0.f;
        #pragma unroll
        for (int c4 = 0; c4 < 16; ++c4) {
            float4 a = ek[c4];
            d0 = fmaf(a.x, zr[4 * c4 + 0], d0);
            d1 = fmaf(a.y, zr[4 * c4 + 1], d1);
            d2 = fmaf(a.z, zr[4 * c4 + 2], d2);
            d3 = fmaf(a.w, zr[4 * c4 + 3], d3);
        }
        float dot  = (d0 + d1) + (d2 + d3);
        float dist = fmaf(-2.0f, dot, e2s[k0 + kk]);
        if (dist < best) { best = dist; bi = k0 + kk; }
    }
    wmin[wid][i] = best; widx[wid][i] = bi;
    __syncthreads();
    if (t < 64) {
        float m = wmin[0][t]; int ix = widx[0][t];
        #pragma unroll
        for (int w = 1; w < 4; ++w) {
            float v = wmin[w][t]; int x = widx[w][t];
            if (v < m) { m = v; ix = x; }
        }
        rowidx[t] = ix;
    }
    __syncthreads();

    float lsum = 0.f;
    const size_t base = (size_t)blk * 4096;
    float* oflat = out + base;
    #pragma unroll
    for (int j = 0; j < 16; ++j) {
        int f  = t + 256 * j;
        int nl = f >> 6, d = f & 63;
        int k  = rowidx[nl];
        float qv = E[(size_t)k * 64 + d];
        float zf = zs[d][nl];
        float df = qv - zf;
        lsum += df * df;
        oflat[f] = qv;
    }
    #pragma unroll
    for (int off = 32; off >= 1; off >>= 1) lsum += __shfl_down(lsum, off, 64);
    if (i == 0) wsum[wid] = lsum;
    __syncthreads();
    if (t == 0) {
        float s = (wsum[0] + wsum[1]) + (wsum[2] + wsum[3]);
        if (partial) partial[blk] = s;
        else         atomicAdd(&out[NDTOT + 1], s);
    }
}

__global__ __launch_bounds__(256) void vq_fin(const float* __restrict__ partial,
                                              float* __restrict__ out, int npart) {
    if (npart > 0) {
        __shared__ float ps[256];
        float s = 0.f;
        for (int qq = threadIdx.x; qq < npart; qq += 256) s += partial[qq];
        ps[threadIdx.x] = s;
        __syncthreads();
        for (int st = 128; st >= 1; st >>= 1) {
            if (threadIdx.x < st) ps[threadIdx.x] += ps[threadIdx.x + st];
            __syncthreads();
        }
        if (threadIdx.x == 0) {
            float mse = ps[0] / (float)NDTOT;
            out[NDTOT]     = 0.25f * mse;   // commitment_loss
            out[NDTOT + 1] = mse;           // codebook_loss
        }
    } else {
        if (threadIdx.x == 0) {
            float mse = out[NDTOT + 1] / (float)NDTOT;
            out[NDTOT]     = 0.25f * mse;
            out[NDTOT + 1] = mse;
        }
    }
}

extern "C" void kernel_launch(void* const* d_in, const int* in_sizes, int n_in,
                              void* d_out, int out_size, void* d_ws, size_t ws_size,
                              hipStream_t stream) {
    const float* z = (const float*)d_in[0];
    const float* E = (const float*)d_in[1];
    float* out = (float*)d_out;

    const size_t EBF_BYTES = (size_t)KCB * 64 * 2;                 // 131072
    const size_t need = EBF_BYTES + 4096 + MBLK * sizeof(float);   // Ebf + he2b + partial

    if (ws_size >= need) {
        unsigned* EbfU = (unsigned*)d_ws;
        short* Ebf  = (short*)d_ws;
        float* he2b = (float*)((char*)d_ws + EBF_BYTES);
        float* partial = (float*)((char*)d_ws + EBF_BYTES + 4096);
        hipLaunchKernelGGL(vq_prep, dim3(4), dim3(256), 0, stream, E, EbfU, he2b);
        hipLaunchKernelGGL(vq_mfma, dim3(MBLK), dim3(256), 0, stream,
                           z, E, Ebf, he2b, out, partial);
        hipLaunchKernelGGL(vq_fin, dim3(1), dim3(256), 0, stream, partial, out, MBLK);
    } else {
        float* partial = (ws_size >= KCB * sizeof(float)) ? (float*)d_ws : nullptr;
        int npart = (partial != nullptr) ? KCB : 0;
        hipLaunchKernelGGL(vq_init, dim3(1), dim3(64), 0, stream, out);
        hipLaunchKernelGGL(vq_main_fp32, dim3(1024), dim3(256), 0, stream, z, E, out, partial);
        hipLaunchKernelGGL(vq_fin, dim3(1), dim3(256), 0, stream, partial, out, npart);
    }
}

// Round 15
// 30.463 us; speedup vs baseline: 6.6127x; 1.0136x over previous
//
#include <hip/hip_runtime.h>

// Problem constants (B=16, C=64, H=64, W=64, K=1024, D=64)
#define HWSZ   4096
#define CCH    64
#define KCB    1024
#define NROW   65536
#define NDTOT  4194304
#define MBLK   256             // main-path blocks
#define BROWS  256             // rows per block (8 waves x 32 rows)
#define WROWS  32              // rows per wave

typedef __attribute__((ext_vector_type(8))) short short8;
typedef __attribute__((ext_vector_type(4))) float f32x4;

typedef const __attribute__((address_space(1))) unsigned gas_u32;
typedef __attribute__((address_space(3))) unsigned las_u32;

__device__ __forceinline__ unsigned short f2bf_rn(float x) {
    union { float f; unsigned u; } v; v.f = x;
    unsigned r = (v.u + 0x7fffu + ((v.u >> 16) & 1u)) >> 16;
    return (unsigned short)r;
}

// ---------- prep: E -> bf16 rows (PRE-SWIZZLED: dword ^ ((k&7)<<2)) + he2b ----------
__global__ __launch_bounds__(256) void vq_prep(const float* __restrict__ E,
                                               unsigned* __restrict__ Ebf,
                                               float* __restrict__ he2b) {
    int k = blockIdx.x * 256 + threadIdx.x;   // 0..1023
    const float4* ep = (const float4*)(E + (size_t)k * 64);
    float s = 0.f;
    const unsigned sw = ((unsigned)k & 7u) << 2;   // T2 swizzle on dword index
    #pragma unroll
    for (int c4 = 0; c4 < 16; ++c4) {
        float4 a = ep[c4];
        s += a.x * a.x + a.y * a.y + a.z * a.z + a.w * a.w;
        unsigned lo = (unsigned)f2bf_rn(a.x) | ((unsigned)f2bf_rn(a.y) << 16);
        unsigned hi = (unsigned)f2bf_rn(a.z) | ((unsigned)f2bf_rn(a.w) << 16);
        unsigned base = (unsigned)k * 32 + 2 * c4;
        Ebf[base ^ sw]       = lo;     // (base+1)^sw == (base^sw)+1 (sw bits >= 2)
        Ebf[(base + 1) ^ sw] = hi;
    }
    he2b[k] = 1.0f + 0.5f * s;
}

// ---------- main: 256 blocks x 512 thr; block = 256 rows; WHOLE codebook in LDS ----------
// Stage the full 128KB swizzled Ebf image + 4KB he2 ONCE via global_load_lds (zero
// staging VGPRs), one barrier, then a barrier-free scan: each of 8 autonomous waves
// sweeps its 32 rows x all 1024 codes from LDS (pure ds_read+MFMA+VALU, compiler
// free to software-pipeline). No fences/tickets (r13 lesson), no chunk round-trips
// (r14 lesson: barrier count wasn't the cost; per-chunk L2 latency exposure was).
__global__ __launch_bounds__(512, 2) void vq_mfma(const float* __restrict__ z,
                                                  const float* __restrict__ E,
                                                  const short* __restrict__ Ebf,
                                                  const float* __restrict__ he2g,
                                                  float* __restrict__ out,
                                                  float* __restrict__ partial) {
    __shared__ short lbs[65536];       // 128 KB: full swizzled codebook image
    __shared__ float he2l[1024];       // 4 KB biases
    __shared__ float wsum[8];

    const int t   = threadIdx.x;       // 0..511
    const int blk = blockIdx.x;        // 0..255
    const int n0  = blk * BROWS;
    const int bb  = n0 >> 12;
    const int wid = t >> 6, lane = t & 63, col = lane & 15, g = lane >> 4;
    const int hwb = (n0 & 4095) + wid * WROWS;      // wave's hw base (within one image)
    const float* zw = z + (size_t)bb * CCH * HWSZ + hwb;

    // ---- stage full codebook: 8192 x 16B slots, 16 per thread (DMA, no VGPRs) ----
    #pragma unroll
    for (int q = 0; q < 16; ++q) {
        int slot = q * 512 + t;        // per-wave dest = uniform base + lane*16  ✓
        __builtin_amdgcn_global_load_lds((gas_u32*)((const char*)Ebf + (size_t)slot * 16),
                                         (las_u32*)((char*)lbs + slot * 16), 16, 0, 0);
    }
    // ---- stage he2: 256 x 16B slots (waves 0-3; wave-uniform branch) ----
    if (t < 256)
        __builtin_amdgcn_global_load_lds((gas_u32*)((const char*)he2g + (size_t)t * 16),
                                         (las_u32*)((char*)he2l + t * 16), 16, 0, 0);

    // ---- A-frags (2 rt x 2 ch) + z^2 partial, direct from global (overlaps DMA) ----
    float z2 = 0.f;
    short8 af[2][2];
    #pragma unroll
    for (int rt = 0; rt < 2; ++rt) {
        #pragma unroll
        for (int ch = 0; ch < 2; ++ch) {
            short8 a;
            #pragma unroll
            for (int j = 0; j < 8; ++j) {
                int c = ch * 32 + g * 8 + j;
                float v = zw[(size_t)c * HWSZ + rt * 16 + col];
                z2 = fmaf(v, v, z2);
                union { float f; unsigned u; } uu; uu.f = v;
                a[j] = (short)((uu.u >> 16) ^ 0x8000u);   // -z, bf16 truncation
            }
            af[rt][ch] = a;
        }
    }

    __syncthreads();   // compiler emits s_waitcnt vmcnt(0) before s_barrier: DMAs landed

    float pk[2][4];
    #pragma unroll
    for (int rt = 0; rt < 2; ++rt)
        #pragma unroll
        for (int r = 0; r < 4; ++r) pk[rt][r] = 3.0e38f;

    // per-lane swizzled LDS read offsets (shorts); code = ct*16 + col, code&7 == col&7
    const int swz = (col & 7) << 3;
    const int ro0 = col * 64 + ((g * 8) ^ swz);
    const int ro1 = col * 64 + ((32 + g * 8) ^ swz);

    // ---- barrier-free scan: 64 code-tiles in 8 groups of 4 cp-pairs ----
    #pragma unroll 2
    for (int cg = 0; cg < 8; ++cg) {
        #pragma unroll
        for (int cp = 0; cp < 4; ++cp) {
            const int ct0 = cg * 8 + cp * 2, ct1 = ct0 + 1;
            const short* Lb0 = lbs + ct0 * 1024;
            const short* Lb1 = lbs + ct1 * 1024;
            short8 b00 = *(const short8*)(Lb0 + ro0);
            short8 b01 = *(const short8*)(Lb0 + ro1);
            short8 b10 = *(const short8*)(Lb1 + ro0);
            short8 b11 = *(const short8*)(Lb1 + ro1);
            const float h0 = he2l[ct0 * 16 + col];       // broadcast read
            const float h1 = he2l[ct1 * 16 + col];
            const unsigned code0 = (unsigned)(ct0 * 16 + col);
            const unsigned code1 = code0 + 16;
            f32x4 hv0 = {h0, h0, h0, h0};
            f32x4 hv1 = {h1, h1, h1, h1};
            #pragma unroll
            for (int rt = 0; rt < 2; ++rt) {
                f32x4 a0 = __builtin_amdgcn_mfma_f32_16x16x32_bf16(af[rt][0], b00, hv0, 0, 0, 0);
                a0 = __builtin_amdgcn_mfma_f32_16x16x32_bf16(af[rt][1], b01, a0, 0, 0, 0);
                f32x4 a1 = __builtin_amdgcn_mfma_f32_16x16x32_bf16(af[rt][0], b10, hv1, 0, 0, 0);
                a1 = __builtin_amdgcn_mfma_f32_16x16x32_bf16(af[rt][1], b11, a1, 0, 0, 0);
                #pragma unroll
                for (int r = 0; r < 4; ++r) {
                    union { float f; unsigned u; } m0, m1;
                    m0.f = a0[r]; m0.u = (m0.u & 0xFFFFFC00u) | code0;  // v_and_or_b32
                    m1.f = a1[r]; m1.u = (m1.u & 0xFFFFFC00u) | code1;
                    pk[rt][r] = fminf(fminf(pk[rt][r], m0.f), m1.f);    // -> v_min3_f32
                }
            }
        }
    }

    // ---- butterfly min over 16 code-columns (all lanes end with row's answer) ----
    #pragma unroll
    for (int rt = 0; rt < 2; ++rt) {
        #pragma unroll
        for (int r = 0; r < 4; ++r) {
            float d = pk[rt][r];
            #pragma unroll
            for (int mask = 1; mask < 16; mask <<= 1)
                d = fminf(d, __shfl_xor(d, mask, 64));
            pk[rt][r] = d;
        }
    }

    // ---- epilogue: output = E rows (k in-register), loss from scores ----
    float lsum = z2;
    const int rowbase = n0 + wid * WROWS;
    #pragma unroll
    for (int rt = 0; rt < 2; ++rt) {
        #pragma unroll
        for (int r = 0; r < 4; ++r) {
            union { float f; unsigned u; } b; b.f = pk[rt][r];
            unsigned kk = b.u & 1023u;
            if (col == 0) {                              // count each row's score once
                union { unsigned u; float f; } sc; sc.u = b.u & 0xFFFFFC00u;
                lsum += 2.0f * (sc.f - 1.0f);            // ||e||^2 - 2 z.e
            }
            int row = rt * 16 + g * 4 + r;
            float4 qv = *(const float4*)(E + (size_t)kk * 64 + col * 4);
            *(float4*)(out + ((size_t)(rowbase + row)) * 64 + col * 4) = qv;
        }
    }

    #pragma unroll
    for (int off = 32; off >= 1; off >>= 1) lsum += __shfl_down(lsum, off, 64);
    if (lane == 0) wsum[wid] = lsum;
    __syncthreads();
    if (t == 0) {
        float s = ((wsum[0] + wsum[1]) + (wsum[2] + wsum[3]))
                + ((wsum[4] + wsum[5]) + (wsum[6] + wsum[7]));
        partial[blk] = s;
    }
}

// ---------- fallback fp32 path (round-1, correctness-proven) ----------
__global__ __launch_bounds__(64) void vq_init(float* out) {
    if (threadIdx.x == 0) { out[NDTOT] = 0.0f; out[NDTOT + 1] = 0.0f; }
}

__global__ __launch_bounds__(256, 4) void vq_main_fp32(const float* __restrict__ z,
                                                       const float* __restrict__ E,
                                                       float* __restrict__ out,
                                                       float* __restrict__ partial) {
    __shared__ float zs[64][65];
    __shared__ float e2s[KCB];
    __shared__ float wmin[4][64];
    __shared__ int   widx[4][64];
    __shared__ int   rowidx[64];
    __shared__ float wsum[4];

    const int t   = threadIdx.x;
    const int blk = blockIdx.x;
    const int n0  = blk << 6;
    const int bb  = n0 >> 12;
    const int hw0 = n0 & 4095;
    const float* zb = z + (size_t)bb * CCH * HWSZ + hw0;

    #pragma unroll
    for (int j = 0; j < 16; ++j) {
        int f = t + 256 * j;
        int c = f >> 6, i = f & 63;
        zs[c][i] = zb[(size_t)c * HWSZ + i];
    }
    for (int qq = t; qq < KCB; qq += 256) {
        const float4* ep = (const float4*)(E + (size_t)qq * 64);
        float s0 = 0.f;
        #pragma unroll
        for (int c4 = 0; c4 < 16; ++c4) {
            float4 a = ep[c4];
            s0 += a.x * a.x + a.y * a.y + a.z * a.z + a.w * a.w;
        }
        e2s[qq] = s0;
    }
    __syncthreads();

    const int i   = t & 63;
    const int wid = t >> 6;
    float zr[64];
    #pragma unroll
    for (int c = 0; c < 64; ++c) zr[c] = zs[c][i];

    float best = 3.4e38f;
    int   bi = 0;
    const int k0 = wid << 8;
    const float* Ew = E + (size_t)k0 * 64;
    for (int kk = 0; kk < 256; ++kk) {
        const float4* ek = (const float4*)(Ew + (size_t)kk * 64);
        float d0 = 0.f, d1 = 0.f, d2 = 0.f, d3 = 0.f;
        #pragma unroll
        for (int c4 = 0; c4 < 16; ++c4) {
            float4 a = ek[c4];
            d0 = fmaf(a.x, zr[4 * c4 + 0], d0);
            d1 = fmaf(a.y, zr[4 * c4 + 1], d1);
            d2 = fmaf(a.z, zr[4 * c4 + 2], d2);
            d3 = fmaf(a.w, zr[4 * c4 + 3], d3);
        }
        float dot  = (d0 + d1) + (d2 + d3);
        float dist = fmaf(-2.0f, dot, e2s[k0 + kk]);
        if (dist < best) { best = dist; bi = k0 + kk; }
    }
    wmin[wid][i] = best; widx[wid][i] = bi;
    __syncthreads();
    if (t < 64) {
        float m = wmin[0][t]; int ix = widx[0][t];
        #pragma unroll
        for (int w = 1; w < 4; ++w) {
            float v = wmin[w][t]; int x = widx[w][t];
            if (v < m) { m = v; ix = x; }
        }
        rowidx[t] = ix;
    }
    __syncthreads();

    float lsum = 0.f;
    const size_t base = (size_t)blk * 4096;
    float* oflat = out + base;
    #pragma unroll
    for (int j = 0; j < 16; ++j) {
        int f  = t + 256 * j;
        int nl = f >> 6, d = f & 63;
        int k  = rowidx[nl];
        float qv = E[(size_t)k * 64 + d];
        float zf = zs[d][nl];
        float df = qv - zf;
        lsum += df * df;
        oflat[f] = qv;
    }
    #pragma unroll
    for (int off = 32; off >= 1; off >>= 1) lsum += __shfl_down(lsum, off, 64);
    if (i == 0) wsum[wid] = lsum;
    __syncthreads();
    if (t == 0) {
        float s = (wsum[0] + wsum[1]) + (wsum[2] + wsum[3]);
        if (partial) partial[blk] = s;
        else         atomicAdd(&out[NDTOT + 1], s);
    }
}

__global__ __launch_bounds__(256) void vq_fin(const float* __restrict__ partial,
                                              float* __restrict__ out, int npart) {
    if (npart > 0) {
        __shared__ float ps[256];
        float s = 0.f;
        for (int qq = threadIdx.x; qq < npart; qq += 256) s += partial[qq];
        ps[threadIdx.x] = s;
        __syncthreads();
        for (int st = 128; st >= 1; st >>= 1) {
            if (threadIdx.x < st) ps[threadIdx.x] += ps[threadIdx.x + st];
            __syncthreads();
        }
        if (threadIdx.x == 0) {
            float mse = ps[0] / (float)NDTOT;
            out[NDTOT]     = 0.25f * mse;   // commitment_loss
            out[NDTOT + 1] = mse;           // codebook_loss
        }
    } else {
        if (threadIdx.x == 0) {
            float mse = out[NDTOT + 1] / (float)NDTOT;
            out[NDTOT]     = 0.25f * mse;
            out[NDTOT + 1] = mse;
        }
    }
}

extern "C" void kernel_launch(void* const* d_in, const int* in_sizes, int n_in,
                              void* d_out, int out_size, void* d_ws, size_t ws_size,
                              hipStream_t stream) {
    const float* z = (const float*)d_in[0];
    const float* E = (const float*)d_in[1];
    float* out = (float*)d_out;

    const size_t EBF_BYTES = (size_t)KCB * 64 * 2;                 // 131072
    const size_t need = EBF_BYTES + 4096 + MBLK * sizeof(float);   // Ebf + he2b + partial

    if (ws_size >= need) {
        unsigned* EbfU = (unsigned*)d_ws;
        short* Ebf  = (short*)d_ws;
        float* he2b = (float*)((char*)d_ws + EBF_BYTES);
        float* partial = (float*)((char*)d_ws + EBF_BYTES + 4096);
        hipLaunchKernelGGL(vq_prep, dim3(4), dim3(256), 0, stream, E, EbfU, he2b);
        hipLaunchKernelGGL(vq_mfma, dim3(MBLK), dim3(512), 0, stream,
                           z, E, Ebf, he2b, out, partial);
        hipLaunchKernelGGL(vq_fin, dim3(1), dim3(256), 0, stream, partial, out, MBLK);
    } else {
        float* partial = (ws_size >= KCB * sizeof(float)) ? (float*)d_ws : nullptr;
        int npart = (partial != nullptr) ? KCB : 0;
        hipLaunchKernelGGL(vq_init, dim3(1), dim3(64), 0, stream, out);
        hipLaunchKernelGGL(vq_main_fp32, dim3(1024), dim3(256), 0, stream, z, E, out, partial);
        hipLaunchKernelGGL(vq_fin, dim3(1), dim3(256), 0, stream, partial, out, npart);
    }
}